// Round 1
// baseline (646.654 us; speedup 1.0000x reference)
//
#include <hip/hip_runtime.h>
#include <math.h>

// ---------------------------------------------------------------------------
// GATPolicy: 3x GATConv (with self loops) + mean-pool + MLP head, fp32.
// Strategy: build CSR-by-dst once per call (counts/scan/scatter), reuse for
// all 3 layers. Aggregation is pull-based (1 wave per dst node), single-pass
// softmax (no max subtraction; e is O(0.1) so exp is safe), zero atomics in
// the hot loops.
// ---------------------------------------------------------------------------

#define LRELU(x) ((x) > 0.f ? (x) : 0.2f * (x))

// ---------------- CSR build ----------------

__global__ void init_counts_kernel(int* __restrict__ cursor, int n) {
    int i = blockIdx.x * blockDim.x + threadIdx.x;
    if (i < n) cursor[i] = 1;  // self loop
}

__global__ void count_kernel(const int* __restrict__ dst, int* __restrict__ cursor, int e) {
    int i = blockIdx.x * blockDim.x + threadIdx.x;
    if (i < e) atomicAdd(&cursor[dst[i]], 1);
}

__global__ __launch_bounds__(256) void scan_block_kernel(
    const int* __restrict__ in, int* __restrict__ out_local,
    int* __restrict__ blockSums, int n) {
    __shared__ int lds[256];
    int i = blockIdx.x * 256 + threadIdx.x;
    int v = (i < n) ? in[i] : 0;
    lds[threadIdx.x] = v;
    __syncthreads();
    for (int off = 1; off < 256; off <<= 1) {
        int t = (threadIdx.x >= off) ? lds[threadIdx.x - off] : 0;
        __syncthreads();
        lds[threadIdx.x] += t;
        __syncthreads();
    }
    if (i < n) out_local[i] = lds[threadIdx.x] - v;  // block-local exclusive
    if (threadIdx.x == 255) blockSums[blockIdx.x] = lds[255];
}

__global__ __launch_bounds__(256) void scan_sums_kernel(int* __restrict__ blockSums, int nb) {
    // nb must be <= 256
    __shared__ int lds[256];
    int v = (threadIdx.x < nb) ? blockSums[threadIdx.x] : 0;
    lds[threadIdx.x] = v;
    __syncthreads();
    for (int off = 1; off < 256; off <<= 1) {
        int t = (threadIdx.x >= off) ? lds[threadIdx.x - off] : 0;
        __syncthreads();
        lds[threadIdx.x] += t;
        __syncthreads();
    }
    if (threadIdx.x < nb) blockSums[threadIdx.x] = lds[threadIdx.x] - v;
    if (threadIdx.x == 255) blockSums[nb] = lds[255];  // total
}

__global__ void scan_finalize_kernel(int* __restrict__ row_ptr, int* __restrict__ cursor,
                                     const int* __restrict__ blockSums, int n, int nb) {
    int i = blockIdx.x * blockDim.x + threadIdx.x;
    if (i < n) {
        int v = row_ptr[i] + blockSums[i >> 8];
        row_ptr[i] = v;
        cursor[i] = v;  // write pointer for scatter
    } else if (i == n) {
        row_ptr[n] = blockSums[nb];
    }
}

__global__ void scatter_kernel(const int* __restrict__ src, const int* __restrict__ dst,
                               int* __restrict__ cursor, int* __restrict__ col,
                               int e, int n) {
    int i = blockIdx.x * blockDim.x + threadIdx.x;
    int total = e + n;
    if (i >= total) return;
    int s, d;
    if (i < e) { s = src[i]; d = dst[i]; }
    else       { s = d = i - e; }
    int pos = atomicAdd(&cursor[d], 1);
    col[pos] = s;
}

// ---------------- GAT node transform: h = x@W, as = h.a_src, ad = h.a_dst ----

template <int K, int OUT, int HEADS>
__global__ __launch_bounds__(OUT) void transform_kernel(
    const float* __restrict__ x, const float* __restrict__ W,
    const float* __restrict__ a_src, const float* __restrict__ a_dst,
    float* __restrict__ h, float* __restrict__ as_o, float* __restrict__ ad_o,
    int n) {
    constexpr int NPB = 8;  // nodes per block (amortizes W reads through L2)
    __shared__ float xs[NPB][K];
    const int tid = threadIdx.x;
    const int node0 = blockIdx.x * NPB;

    for (int idx = tid; idx < NPB * K; idx += OUT) {
        int ni = idx / K, k = idx - ni * K;
        int ng = node0 + ni;
        xs[ni][k] = (ng < n) ? x[(size_t)ng * K + k] : 0.f;
    }
    __syncthreads();

    float acc[NPB];
#pragma unroll
    for (int i = 0; i < NPB; i++) acc[i] = 0.f;
    for (int k = 0; k < K; k++) {
        float wk = W[k * OUT + tid];
#pragma unroll
        for (int i = 0; i < NPB; i++) acc[i] += xs[i][k] * wk;
    }

    const int lane = tid & 63;
    const int head = (HEADS == 2) ? (tid >> 6) : 0;
    const float av = a_src[tid];
    const float dv = a_dst[tid];
#pragma unroll
    for (int i = 0; i < NPB; i++) {
        int ng = node0 + i;
        if (ng >= n) break;  // uniform across block
        h[(size_t)ng * OUT + tid] = acc[i];
        float ps = acc[i] * av, pd = acc[i] * dv;
        for (int off = 32; off; off >>= 1) {
            ps += __shfl_xor(ps, off, 64);
            pd += __shfl_xor(pd, off, 64);
        }
        if (lane == 0) {
            as_o[ng * HEADS + head] = ps;
            ad_o[ng * HEADS + head] = pd;
        }
    }
}

// ---------------- GAT aggregation: one wave per dst node -------------------
// out[n] = sum_j exp(lrelu(as[src_j]+ad[n])) * h[src_j] / sum_j exp(...) + b
// Lane l owns channel l (head 0) and l+64 (head 1).

template <int CT, int HEADS, int ACT>  // ACT: 0 none, 1 elu
__global__ __launch_bounds__(256) void agg_kernel(
    const int* __restrict__ row_ptr, const int* __restrict__ col,
    const float* __restrict__ h, const float* __restrict__ as_,
    const float* __restrict__ ad_, const float* __restrict__ bias,
    float* __restrict__ out, int n) {
    int wid = blockIdx.x * (blockDim.x >> 6) + (threadIdx.x >> 6);
    int lane = threadIdx.x & 63;
    if (wid >= n) return;
    int beg = row_ptr[wid], end = row_ptr[wid + 1];
    float ad0 = ad_[wid * HEADS + 0];
    float ad1 = (HEADS == 2) ? ad_[wid * HEADS + 1] : 0.f;
    float acc0 = 0.f, acc1 = 0.f, den0 = 0.f, den1 = 0.f;
    for (int j = beg; j < end; j++) {
        int s = col[j];
        float as0 = as_[s * HEADS + 0];
        float e0 = LRELU(as0 + ad0);
        float w0 = expf(e0);
        den0 += w0;
        acc0 += w0 * h[(size_t)s * CT + lane];
        if (HEADS == 2) {
            float as1 = as_[s * 2 + 1];
            float e1 = LRELU(as1 + ad1);
            float w1 = expf(e1);
            den1 += w1;
            acc1 += w1 * h[(size_t)s * CT + 64 + lane];
        }
    }
    float o0 = acc0 / (den0 + 1e-16f) + bias[lane];
    if (ACT) o0 = o0 > 0.f ? o0 : expm1f(o0);
    out[(size_t)wid * CT + lane] = o0;
    if (HEADS == 2) {
        float o1 = acc1 / (den1 + 1e-16f) + bias[64 + lane];
        if (ACT) o1 = o1 > 0.f ? o1 : expm1f(o1);
        out[(size_t)wid * CT + 64 + lane] = o1;
    }
}

// ---------------- mean pool over sorted batch ------------------------------
// One wave handles 16 contiguous nodes; batch is sorted, so we accumulate
// runs locally and flush ~1 atomic per run.

__global__ __launch_bounds__(256) void pool_kernel(
    const float* __restrict__ x, const int* __restrict__ batch,
    float* __restrict__ pooled, float* __restrict__ cnt, int n) {
    const int NPW = 16;
    int wid = blockIdx.x * (blockDim.x >> 6) + (threadIdx.x >> 6);
    int lane = threadIdx.x & 63;
    int start = wid * NPW;
    if (start >= n) return;
    int end = min(start + NPW, n);
    float acc = 0.f, c = 0.f;
    int cur = -1;
    for (int i = start; i < end; i++) {
        int b = batch[i];
        if (b != cur) {
            if (cur >= 0) {
                atomicAdd(&pooled[cur * 64 + lane], acc);
                if (lane == 0) atomicAdd(&cnt[cur], c);
            }
            cur = b;
            acc = 0.f;
            c = 0.f;
        }
        acc += x[(size_t)i * 64 + lane];
        c += 1.f;
    }
    if (cur >= 0) {
        atomicAdd(&pooled[cur * 64 + lane], acc);
        if (lane == 0) atomicAdd(&cnt[cur], c);
    }
}

// ---------------- MLP head: one block per graph row ------------------------

__global__ __launch_bounds__(256) void mlp_kernel(
    const float* __restrict__ pooled, const float* __restrict__ cnt,
    const float* __restrict__ obs,
    const float* __restrict__ Ws1, const float* __restrict__ bs1,
    const float* __restrict__ ln_g, const float* __restrict__ ln_b,
    const float* __restrict__ Ws2, const float* __restrict__ bs2,
    const float* __restrict__ Wa, const float* __restrict__ ba,
    const float* __restrict__ Wc, const float* __restrict__ bc,
    float* __restrict__ out_logits, float* __restrict__ out_value) {
    int b = blockIdx.x;
    int t = threadIdx.x;
    __shared__ float comb[192];
    __shared__ float red[256];
    __shared__ float hs[256];

    if (t < 64) {
        float c = cnt[b];
        c = c > 1.f ? c : 1.f;
        comb[t] = pooled[b * 64 + t] / c;
    } else if (t < 192) {
        comb[t] = obs[b * 128 + (t - 64)];
    }
    __syncthreads();

    float acc = bs1[t];
    for (int k = 0; k < 192; k++) acc += comb[k] * Ws1[k * 256 + t];

    // layernorm over 256 features
    red[t] = acc;
    __syncthreads();
    for (int off = 128; off; off >>= 1) {
        if (t < off) red[t] += red[t + off];
        __syncthreads();
    }
    float mu = red[0] / 256.f;
    __syncthreads();
    float d = acc - mu;
    red[t] = d * d;
    __syncthreads();
    for (int off = 128; off; off >>= 1) {
        if (t < off) red[t] += red[t + off];
        __syncthreads();
    }
    float var = red[0] / 256.f;
    float hn = d * rsqrtf(var + 1e-5f) * ln_g[t] + ln_b[t];
    hn = hn > 0.f ? hn : 0.f;
    __syncthreads();
    hs[t] = hn;
    __syncthreads();

    float acc2 = bs2[t];
    for (int k = 0; k < 256; k++) acc2 += hs[k] * Ws2[k * 256 + t];
    acc2 = acc2 > 0.f ? acc2 : 0.f;
    __syncthreads();
    hs[t] = acc2;
    __syncthreads();

    if (t < 16) {
        float a = ba[t];
        for (int k = 0; k < 256; k++) a += hs[k] * Wa[k * 16 + t];
        out_logits[b * 16 + t] = a;
    } else if (t == 16) {
        float v = bc[0];
        for (int k = 0; k < 256; k++) v += hs[k] * Wc[k];
        out_value[b] = v;
    }
}

// ---------------------------------------------------------------------------

extern "C" void kernel_launch(void* const* d_in, const int* in_sizes, int n_in,
                              void* d_out, int out_size, void* d_ws, size_t ws_size,
                              hipStream_t stream) {
    const float* obs    = (const float*)d_in[0];
    const float* nf     = (const float*)d_in[1];
    const int*   ei     = (const int*)d_in[2];
    const int*   batch  = (const int*)d_in[3];
    const float* W0     = (const float*)d_in[4];
    const float* a_src0 = (const float*)d_in[5];
    const float* a_dst0 = (const float*)d_in[6];
    const float* b0     = (const float*)d_in[7];
    const float* W1     = (const float*)d_in[8];
    const float* a_src1 = (const float*)d_in[9];
    const float* a_dst1 = (const float*)d_in[10];
    const float* b1     = (const float*)d_in[11];
    const float* W2     = (const float*)d_in[12];
    const float* a_src2 = (const float*)d_in[13];
    const float* a_dst2 = (const float*)d_in[14];
    const float* b2     = (const float*)d_in[15];
    const float* Ws1    = (const float*)d_in[16];
    const float* bs1    = (const float*)d_in[17];
    const float* ln_g   = (const float*)d_in[18];
    const float* ln_b   = (const float*)d_in[19];
    const float* Ws2    = (const float*)d_in[20];
    const float* bs2    = (const float*)d_in[21];
    const float* Wa     = (const float*)d_in[22];
    const float* ba     = (const float*)d_in[23];
    const float* Wc     = (const float*)d_in[24];
    const float* bc     = (const float*)d_in[25];

    const int N = in_sizes[3];
    const int E = in_sizes[2] / 2;
    const int B = in_sizes[0] / 128;
    const int* src = ei;
    const int* dstp = ei + E;

    // workspace carve (256B aligned)
    char* p = (char*)d_ws;
    auto alloc = [&](size_t bytes) -> void* {
        void* r = (void*)p;
        p += (bytes + 255) & ~(size_t)255;
        return r;
    };
    int nb = (N + 255) / 256;
    int*   cursor    = (int*)alloc((size_t)N * 4);
    int*   row_ptr   = (int*)alloc((size_t)(N + 1) * 4);
    int*   blockSums = (int*)alloc((size_t)(nb + 1) * 4);
    int*   col       = (int*)alloc((size_t)(E + N) * 4);
    float* hbuf      = (float*)alloc((size_t)N * 128 * 4);
    float* xbuf      = (float*)alloc((size_t)N * 128 * 4);
    float* as_       = (float*)alloc((size_t)N * 2 * 4);
    float* ad_       = (float*)alloc((size_t)N * 2 * 4);
    float* pooled    = (float*)alloc((size_t)(B * 64 + B) * 4);
    float* cnt       = pooled + (size_t)B * 64;

    float* out_logits = (float*)d_out;
    float* out_value  = out_logits + (size_t)B * 16;

    // ---- CSR build (by dst, includes self loops) ----
    init_counts_kernel<<<(N + 255) / 256, 256, 0, stream>>>(cursor, N);
    count_kernel<<<(E + 255) / 256, 256, 0, stream>>>(dstp, cursor, E);
    scan_block_kernel<<<nb, 256, 0, stream>>>(cursor, row_ptr, blockSums, N);
    scan_sums_kernel<<<1, 256, 0, stream>>>(blockSums, nb);
    scan_finalize_kernel<<<(N + 1 + 255) / 256, 256, 0, stream>>>(row_ptr, cursor, blockSums, N, nb);
    scatter_kernel<<<(E + N + 255) / 256, 256, 0, stream>>>(src, dstp, cursor, col, E, N);

    // ---- zero pooled/cnt ----
    hipMemsetAsync(pooled, 0, (size_t)(B * 64 + B) * 4, stream);

    // ---- GAT layer 0: in=8 -> h=[N,2,64] concat, elu ----
    transform_kernel<8, 128, 2><<<(N + 7) / 8, 128, 0, stream>>>(
        nf, W0, a_src0, a_dst0, hbuf, as_, ad_, N);
    agg_kernel<128, 2, 1><<<(N + 3) / 4, 256, 0, stream>>>(
        row_ptr, col, hbuf, as_, ad_, b0, xbuf, N);

    // ---- GAT layer 1: in=128 -> concat, elu ----
    transform_kernel<128, 128, 2><<<(N + 7) / 8, 128, 0, stream>>>(
        xbuf, W1, a_src1, a_dst1, hbuf, as_, ad_, N);
    agg_kernel<128, 2, 1><<<(N + 3) / 4, 256, 0, stream>>>(
        row_ptr, col, hbuf, as_, ad_, b1, xbuf, N);

    // ---- GAT layer 2: in=128 -> heads=1, out=64, no concat, no act ----
    transform_kernel<128, 64, 1><<<(N + 7) / 8, 64, 0, stream>>>(
        xbuf, W2, a_src2, a_dst2, hbuf, as_, ad_, N);
    agg_kernel<64, 1, 0><<<(N + 3) / 4, 256, 0, stream>>>(
        row_ptr, col, hbuf, as_, ad_, b2, xbuf, N);

    // ---- mean pool + MLP head ----
    {
        int waves = (N + 15) / 16;
        int blocks = (waves + 3) / 4;
        pool_kernel<<<blocks, 256, 0, stream>>>(xbuf, batch, pooled, cnt, N);
    }
    mlp_kernel<<<B, 256, 0, stream>>>(pooled, cnt, obs, Ws1, bs1, ln_g, ln_b,
                                      Ws2, bs2, Wa, ba, Wc, bc,
                                      out_logits, out_value);
}

// Round 2
// 542.933 us; speedup vs baseline: 1.1910x; 1.1910x over previous
//
#include <hip/hip_runtime.h>
#include <math.h>

// ---------------------------------------------------------------------------
// GATPolicy: 3x GATConv (with self loops) + mean-pool + MLP head, fp32.
// CSR-by-dst built once per call; aggregation is pull-based, one wave per
// (node, head). Per-node softmax weights are computed VECTORIZED across the
// wave's lanes (one lane per edge), then the serial loop is just
// shfl-broadcast + row-gather + fmac.
// ---------------------------------------------------------------------------

#define LRELU(x) ((x) > 0.f ? (x) : 0.2f * (x))

// ---------------- CSR build ----------------

__global__ void init_counts_kernel(int* __restrict__ cursor, int n) {
    int i = blockIdx.x * blockDim.x + threadIdx.x;
    if (i < n) cursor[i] = 1;  // self loop
}

__global__ void count_kernel(const int* __restrict__ dst, int* __restrict__ cursor, int e) {
    int i = blockIdx.x * blockDim.x + threadIdx.x;
    if (i < e) atomicAdd(&cursor[dst[i]], 1);
}

__global__ __launch_bounds__(256) void scan_block_kernel(
    const int* __restrict__ in, int* __restrict__ out_local,
    int* __restrict__ blockSums, int n) {
    __shared__ int lds[256];
    int i = blockIdx.x * 256 + threadIdx.x;
    int v = (i < n) ? in[i] : 0;
    lds[threadIdx.x] = v;
    __syncthreads();
    for (int off = 1; off < 256; off <<= 1) {
        int t = (threadIdx.x >= off) ? lds[threadIdx.x - off] : 0;
        __syncthreads();
        lds[threadIdx.x] += t;
        __syncthreads();
    }
    if (i < n) out_local[i] = lds[threadIdx.x] - v;  // block-local exclusive
    if (threadIdx.x == 255) blockSums[blockIdx.x] = lds[255];
}

__global__ __launch_bounds__(256) void scan_sums_kernel(int* __restrict__ blockSums, int nb) {
    // nb must be <= 256
    __shared__ int lds[256];
    int v = (threadIdx.x < nb) ? blockSums[threadIdx.x] : 0;
    lds[threadIdx.x] = v;
    __syncthreads();
    for (int off = 1; off < 256; off <<= 1) {
        int t = (threadIdx.x >= off) ? lds[threadIdx.x - off] : 0;
        __syncthreads();
        lds[threadIdx.x] += t;
        __syncthreads();
    }
    if (threadIdx.x < nb) blockSums[threadIdx.x] = lds[threadIdx.x] - v;
    if (threadIdx.x == 255) blockSums[nb] = lds[255];  // total
}

__global__ void scan_finalize_kernel(int* __restrict__ row_ptr, int* __restrict__ cursor,
                                     const int* __restrict__ blockSums, int n, int nb) {
    int i = blockIdx.x * blockDim.x + threadIdx.x;
    if (i < n) {
        int v = row_ptr[i] + blockSums[i >> 8];
        row_ptr[i] = v;
        cursor[i] = v;  // write pointer for scatter
    } else if (i == n) {
        row_ptr[n] = blockSums[nb];
    }
}

__global__ void scatter_kernel(const int* __restrict__ src, const int* __restrict__ dst,
                               int* __restrict__ cursor, int* __restrict__ col,
                               int e, int n) {
    int i = blockIdx.x * blockDim.x + threadIdx.x;
    int total = e + n;
    if (i >= total) return;
    int s, d;
    if (i < e) { s = src[i]; d = dst[i]; }
    else       { s = d = i - e; }
    int pos = atomicAdd(&cursor[d], 1);
    col[pos] = s;
}

// ---------------- GAT node transform: h = x@W, as = h.a_src, ad = h.a_dst ----

template <int K, int OUT, int HEADS>
__global__ __launch_bounds__(OUT) void transform_kernel(
    const float* __restrict__ x, const float* __restrict__ W,
    const float* __restrict__ a_src, const float* __restrict__ a_dst,
    float* __restrict__ h, float* __restrict__ as_o, float* __restrict__ ad_o,
    int n) {
    constexpr int NPB = 8;  // nodes per block (amortizes W reads through L2)
    __shared__ float xs[NPB][K];
    const int tid = threadIdx.x;
    const int node0 = blockIdx.x * NPB;

    for (int idx = tid; idx < NPB * K; idx += OUT) {
        int ni = idx / K, k = idx - ni * K;
        int ng = node0 + ni;
        xs[ni][k] = (ng < n) ? x[(size_t)ng * K + k] : 0.f;
    }
    __syncthreads();

    float acc[NPB];
#pragma unroll
    for (int i = 0; i < NPB; i++) acc[i] = 0.f;
    for (int k = 0; k < K; k++) {
        float wk = W[k * OUT + tid];
#pragma unroll
        for (int i = 0; i < NPB; i++) acc[i] += xs[i][k] * wk;
    }

    const int lane = tid & 63;
    const int head = (HEADS == 2) ? (tid >> 6) : 0;
    const float av = a_src[tid];
    const float dv = a_dst[tid];
#pragma unroll
    for (int i = 0; i < NPB; i++) {
        int ng = node0 + i;
        if (ng >= n) break;  // uniform across block
        h[(size_t)ng * OUT + tid] = acc[i];
        float ps = acc[i] * av, pd = acc[i] * dv;
        for (int off = 32; off; off >>= 1) {
            ps += __shfl_xor(ps, off, 64);
            pd += __shfl_xor(pd, off, 64);
        }
        if (lane == 0) {
            as_o[ng * HEADS + head] = ps;
            ad_o[ng * HEADS + head] = pd;
        }
    }
}

// ---------------- GAT aggregation: one wave per (node, head) ---------------
// Softmax weights for all edges of the node are computed vectorized across
// lanes (lane j owns edge j of the segment chunk); the serial loop is just
// shfl-broadcast + 256B row gather + fmac. Lane l owns channel l.

template <int CT, int HEADS, int ACT>  // ACT: 0 none, 1 elu
__global__ __launch_bounds__(256) void agg_kernel(
    const int* __restrict__ row_ptr, const int* __restrict__ col,
    const float* __restrict__ h, const float* __restrict__ as_,
    const float* __restrict__ ad_, const float* __restrict__ bias,
    float* __restrict__ out, int n) {
    const int gwid = blockIdx.x * 4 + (threadIdx.x >> 6);
    const int lane = threadIdx.x & 63;
    const int node = (HEADS == 2) ? (gwid >> 1) : gwid;
    const int head = (HEADS == 2) ? (gwid & 1) : 0;
    if (node >= n) return;

    const int beg = row_ptr[node], end = row_ptr[node + 1];
    const float adv = ad_[node * HEADS + head];
    const float* __restrict__ hrow = h + head * 64 + lane;  // + s*CT per edge

    float acc = 0.f, den = 0.f;
    for (int base = beg; base < end; base += 64) {
        int cnt = end - base;
        if (cnt > 64) cnt = 64;
        // vectorized per-edge weight computation: lane j handles edge base+j
        int s = 0;
        float w = 0.f;
        if (lane < cnt) {
            s = col[base + lane];
            float xv = as_[s * HEADS + head] + adv;
            w = __expf(LRELU(xv));
        }
        int j = 0;
        for (; j + 1 < cnt; j += 2) {
            int s0 = __shfl(s, j);
            int s1 = __shfl(s, j + 1);
            float w0 = __shfl(w, j);
            float w1 = __shfl(w, j + 1);
            float h0 = hrow[(size_t)s0 * CT];
            float h1 = hrow[(size_t)s1 * CT];
            den += w0 + w1;
            acc += w0 * h0;
            acc += w1 * h1;
        }
        if (j < cnt) {
            int s0 = __shfl(s, j);
            float w0 = __shfl(w, j);
            den += w0;
            acc += w0 * hrow[(size_t)s0 * CT];
        }
    }

    float o = acc / (den + 1e-16f) + bias[head * 64 + lane];
    if (ACT) o = o > 0.f ? o : expm1f(o);
    out[(size_t)node * CT + head * 64 + lane] = o;
}

// ---------------- mean pool over sorted batch ------------------------------

__global__ __launch_bounds__(256) void pool_kernel(
    const float* __restrict__ x, const int* __restrict__ batch,
    float* __restrict__ pooled, float* __restrict__ cnt, int n) {
    const int NPW = 16;
    int wid = blockIdx.x * (blockDim.x >> 6) + (threadIdx.x >> 6);
    int lane = threadIdx.x & 63;
    int start = wid * NPW;
    if (start >= n) return;
    int end = min(start + NPW, n);
    float acc = 0.f, c = 0.f;
    int cur = -1;
    for (int i = start; i < end; i++) {
        int b = batch[i];
        if (b != cur) {
            if (cur >= 0) {
                atomicAdd(&pooled[cur * 64 + lane], acc);
                if (lane == 0) atomicAdd(&cnt[cur], c);
            }
            cur = b;
            acc = 0.f;
            c = 0.f;
        }
        acc += x[(size_t)i * 64 + lane];
        c += 1.f;
    }
    if (cur >= 0) {
        atomicAdd(&pooled[cur * 64 + lane], acc);
        if (lane == 0) atomicAdd(&cnt[cur], c);
    }
}

// ---------------- MLP head: one block per graph row ------------------------

__global__ __launch_bounds__(256) void mlp_kernel(
    const float* __restrict__ pooled, const float* __restrict__ cnt,
    const float* __restrict__ obs,
    const float* __restrict__ Ws1, const float* __restrict__ bs1,
    const float* __restrict__ ln_g, const float* __restrict__ ln_b,
    const float* __restrict__ Ws2, const float* __restrict__ bs2,
    const float* __restrict__ Wa, const float* __restrict__ ba,
    const float* __restrict__ Wc, const float* __restrict__ bc,
    float* __restrict__ out_logits, float* __restrict__ out_value) {
    int b = blockIdx.x;
    int t = threadIdx.x;
    __shared__ float comb[192];
    __shared__ float red[256];
    __shared__ float hs[256];

    if (t < 64) {
        float c = cnt[b];
        c = c > 1.f ? c : 1.f;
        comb[t] = pooled[b * 64 + t] / c;
    } else if (t < 192) {
        comb[t] = obs[b * 128 + (t - 64)];
    }
    __syncthreads();

    float acc = bs1[t];
    for (int k = 0; k < 192; k++) acc += comb[k] * Ws1[k * 256 + t];

    // layernorm over 256 features
    red[t] = acc;
    __syncthreads();
    for (int off = 128; off; off >>= 1) {
        if (t < off) red[t] += red[t + off];
        __syncthreads();
    }
    float mu = red[0] / 256.f;
    __syncthreads();
    float d = acc - mu;
    red[t] = d * d;
    __syncthreads();
    for (int off = 128; off; off >>= 1) {
        if (t < off) red[t] += red[t + off];
        __syncthreads();
    }
    float var = red[0] / 256.f;
    float hn = d * rsqrtf(var + 1e-5f) * ln_g[t] + ln_b[t];
    hn = hn > 0.f ? hn : 0.f;
    __syncthreads();
    hs[t] = hn;
    __syncthreads();

    float acc2 = bs2[t];
    for (int k = 0; k < 256; k++) acc2 += hs[k] * Ws2[k * 256 + t];
    acc2 = acc2 > 0.f ? acc2 : 0.f;
    __syncthreads();
    hs[t] = acc2;
    __syncthreads();

    if (t < 16) {
        float a = ba[t];
        for (int k = 0; k < 256; k++) a += hs[k] * Wa[k * 16 + t];
        out_logits[b * 16 + t] = a;
    } else if (t == 16) {
        float v = bc[0];
        for (int k = 0; k < 256; k++) v += hs[k] * Wc[k];
        out_value[b] = v;
    }
}

// ---------------------------------------------------------------------------

extern "C" void kernel_launch(void* const* d_in, const int* in_sizes, int n_in,
                              void* d_out, int out_size, void* d_ws, size_t ws_size,
                              hipStream_t stream) {
    const float* obs    = (const float*)d_in[0];
    const float* nf     = (const float*)d_in[1];
    const int*   ei     = (const int*)d_in[2];
    const int*   batch  = (const int*)d_in[3];
    const float* W0     = (const float*)d_in[4];
    const float* a_src0 = (const float*)d_in[5];
    const float* a_dst0 = (const float*)d_in[6];
    const float* b0     = (const float*)d_in[7];
    const float* W1     = (const float*)d_in[8];
    const float* a_src1 = (const float*)d_in[9];
    const float* a_dst1 = (const float*)d_in[10];
    const float* b1     = (const float*)d_in[11];
    const float* W2     = (const float*)d_in[12];
    const float* a_src2 = (const float*)d_in[13];
    const float* a_dst2 = (const float*)d_in[14];
    const float* b2     = (const float*)d_in[15];
    const float* Ws1    = (const float*)d_in[16];
    const float* bs1    = (const float*)d_in[17];
    const float* ln_g   = (const float*)d_in[18];
    const float* ln_b   = (const float*)d_in[19];
    const float* Ws2    = (const float*)d_in[20];
    const float* bs2    = (const float*)d_in[21];
    const float* Wa     = (const float*)d_in[22];
    const float* ba     = (const float*)d_in[23];
    const float* Wc     = (const float*)d_in[24];
    const float* bc     = (const float*)d_in[25];

    const int N = in_sizes[3];
    const int E = in_sizes[2] / 2;
    const int B = in_sizes[0] / 128;
    const int* src = ei;
    const int* dstp = ei + E;

    // workspace carve (256B aligned)
    char* p = (char*)d_ws;
    auto alloc = [&](size_t bytes) -> void* {
        void* r = (void*)p;
        p += (bytes + 255) & ~(size_t)255;
        return r;
    };
    int nb = (N + 255) / 256;
    int*   cursor    = (int*)alloc((size_t)N * 4);
    int*   row_ptr   = (int*)alloc((size_t)(N + 1) * 4);
    int*   blockSums = (int*)alloc((size_t)(nb + 1) * 4);
    int*   col       = (int*)alloc((size_t)(E + N) * 4);
    float* hbuf      = (float*)alloc((size_t)N * 128 * 4);
    float* xbuf      = (float*)alloc((size_t)N * 128 * 4);
    float* as_       = (float*)alloc((size_t)N * 2 * 4);
    float* ad_       = (float*)alloc((size_t)N * 2 * 4);
    float* pooled    = (float*)alloc((size_t)(B * 64 + B) * 4);
    float* cnt       = pooled + (size_t)B * 64;

    float* out_logits = (float*)d_out;
    float* out_value  = out_logits + (size_t)B * 16;

    // ---- CSR build (by dst, includes self loops) ----
    init_counts_kernel<<<(N + 255) / 256, 256, 0, stream>>>(cursor, N);
    count_kernel<<<(E + 255) / 256, 256, 0, stream>>>(dstp, cursor, E);
    scan_block_kernel<<<nb, 256, 0, stream>>>(cursor, row_ptr, blockSums, N);
    scan_sums_kernel<<<1, 256, 0, stream>>>(blockSums, nb);
    scan_finalize_kernel<<<(N + 1 + 255) / 256, 256, 0, stream>>>(row_ptr, cursor, blockSums, N, nb);
    scatter_kernel<<<(E + N + 255) / 256, 256, 0, stream>>>(src, dstp, cursor, col, E, N);

    // ---- zero pooled/cnt ----
    hipMemsetAsync(pooled, 0, (size_t)(B * 64 + B) * 4, stream);

    // ---- GAT layer 0: in=8 -> h=[N,2,64] concat, elu ----
    transform_kernel<8, 128, 2><<<(N + 7) / 8, 128, 0, stream>>>(
        nf, W0, a_src0, a_dst0, hbuf, as_, ad_, N);
    agg_kernel<128, 2, 1><<<(2 * N + 3) / 4, 256, 0, stream>>>(
        row_ptr, col, hbuf, as_, ad_, b0, xbuf, N);

    // ---- GAT layer 1: in=128 -> concat, elu ----
    transform_kernel<128, 128, 2><<<(N + 7) / 8, 128, 0, stream>>>(
        xbuf, W1, a_src1, a_dst1, hbuf, as_, ad_, N);
    agg_kernel<128, 2, 1><<<(2 * N + 3) / 4, 256, 0, stream>>>(
        row_ptr, col, hbuf, as_, ad_, b1, xbuf, N);

    // ---- GAT layer 2: in=128 -> heads=1, out=64, no concat, no act ----
    transform_kernel<128, 64, 1><<<(N + 7) / 8, 64, 0, stream>>>(
        xbuf, W2, a_src2, a_dst2, hbuf, as_, ad_, N);
    agg_kernel<64, 1, 0><<<(N + 3) / 4, 256, 0, stream>>>(
        row_ptr, col, hbuf, as_, ad_, b2, xbuf, N);

    // ---- mean pool + MLP head ----
    {
        int waves = (N + 15) / 16;
        int blocks = (waves + 3) / 4;
        pool_kernel<<<blocks, 256, 0, stream>>>(xbuf, batch, pooled, cnt, N);
    }
    mlp_kernel<<<B, 256, 0, stream>>>(pooled, cnt, obs, Ws1, bs1, ln_g, ln_b,
                                      Ws2, bs2, Wa, ba, Wc, bc,
                                      out_logits, out_value);
}

// Round 3
// 525.775 us; speedup vs baseline: 1.2299x; 1.0326x over previous
//
#include <hip/hip_runtime.h>
#include <math.h>

// ---------------------------------------------------------------------------
// GATPolicy: 3x GATConv (with self loops) + mean-pool + MLP head, fp32.
// CSR-by-dst built once per call; aggregation is pull-based, one wave per
// (node, head). Softmax weights vectorized across lanes; the serial edge loop
// uses readlane->SGPR broadcasts so the row gather is saddr-form loads with
// SALU address math; den is a once-per-chunk wave reduction.
// ---------------------------------------------------------------------------

#define LRELU(x) ((x) > 0.f ? (x) : 0.2f * (x))

__device__ __forceinline__ float readlane_f(float v, int lane) {
    return __int_as_float(__builtin_amdgcn_readlane(__float_as_int(v), lane));
}

// ---------------- CSR build ----------------

__global__ void init_counts_kernel(int* __restrict__ cursor, int n) {
    int i = blockIdx.x * blockDim.x + threadIdx.x;
    if (i < n) cursor[i] = 1;  // self loop
}

__global__ void count_kernel(const int* __restrict__ dst, int* __restrict__ cursor, int e) {
    int i = blockIdx.x * blockDim.x + threadIdx.x;
    if (i < e) atomicAdd(&cursor[dst[i]], 1);
}

__global__ __launch_bounds__(256) void scan_block_kernel(
    const int* __restrict__ in, int* __restrict__ out_local,
    int* __restrict__ blockSums, int n) {
    __shared__ int lds[256];
    int i = blockIdx.x * 256 + threadIdx.x;
    int v = (i < n) ? in[i] : 0;
    lds[threadIdx.x] = v;
    __syncthreads();
    for (int off = 1; off < 256; off <<= 1) {
        int t = (threadIdx.x >= off) ? lds[threadIdx.x - off] : 0;
        __syncthreads();
        lds[threadIdx.x] += t;
        __syncthreads();
    }
    if (i < n) out_local[i] = lds[threadIdx.x] - v;  // block-local exclusive
    if (threadIdx.x == 255) blockSums[blockIdx.x] = lds[255];
}

__global__ __launch_bounds__(256) void scan_sums_kernel(int* __restrict__ blockSums, int nb) {
    // nb must be <= 256
    __shared__ int lds[256];
    int v = (threadIdx.x < nb) ? blockSums[threadIdx.x] : 0;
    lds[threadIdx.x] = v;
    __syncthreads();
    for (int off = 1; off < 256; off <<= 1) {
        int t = (threadIdx.x >= off) ? lds[threadIdx.x - off] : 0;
        __syncthreads();
        lds[threadIdx.x] += t;
        __syncthreads();
    }
    if (threadIdx.x < nb) blockSums[threadIdx.x] = lds[threadIdx.x] - v;
    if (threadIdx.x == 255) blockSums[nb] = lds[255];  // total
}

__global__ void scan_finalize_kernel(int* __restrict__ row_ptr, int* __restrict__ cursor,
                                     const int* __restrict__ blockSums, int n, int nb) {
    int i = blockIdx.x * blockDim.x + threadIdx.x;
    if (i < n) {
        int v = row_ptr[i] + blockSums[i >> 8];
        row_ptr[i] = v;
        cursor[i] = v;  // write pointer for scatter
    } else if (i == n) {
        row_ptr[n] = blockSums[nb];
    }
}

__global__ void scatter_kernel(const int* __restrict__ src, const int* __restrict__ dst,
                               int* __restrict__ cursor, int* __restrict__ col,
                               int e, int n) {
    int i = blockIdx.x * blockDim.x + threadIdx.x;
    int total = e + n;
    if (i >= total) return;
    int s, d;
    if (i < e) { s = src[i]; d = dst[i]; }
    else       { s = d = i - e; }
    int pos = atomicAdd(&cursor[d], 1);
    col[pos] = s;
}

// ---------------- GAT node transform: h = x@W, as = h.a_src, ad = h.a_dst ----

template <int K, int OUT, int HEADS>
__global__ __launch_bounds__(OUT) void transform_kernel(
    const float* __restrict__ x, const float* __restrict__ W,
    const float* __restrict__ a_src, const float* __restrict__ a_dst,
    float* __restrict__ h, float* __restrict__ as_o, float* __restrict__ ad_o,
    int n) {
    constexpr int NPB = 8;  // nodes per block (amortizes W reads through L2)
    __shared__ float xs[NPB][K];
    const int tid = threadIdx.x;
    const int node0 = blockIdx.x * NPB;

    for (int idx = tid; idx < NPB * K; idx += OUT) {
        int ni = idx / K, k = idx - ni * K;
        int ng = node0 + ni;
        xs[ni][k] = (ng < n) ? x[(size_t)ng * K + k] : 0.f;
    }
    __syncthreads();

    float acc[NPB];
#pragma unroll
    for (int i = 0; i < NPB; i++) acc[i] = 0.f;
    for (int k = 0; k < K; k++) {
        float wk = W[k * OUT + tid];
#pragma unroll
        for (int i = 0; i < NPB; i++) acc[i] += xs[i][k] * wk;
    }

    const int lane = tid & 63;
    const int head = (HEADS == 2) ? (tid >> 6) : 0;
    const float av = a_src[tid];
    const float dv = a_dst[tid];
#pragma unroll
    for (int i = 0; i < NPB; i++) {
        int ng = node0 + i;
        if (ng >= n) break;  // uniform across block
        h[(size_t)ng * OUT + tid] = acc[i];
        float ps = acc[i] * av, pd = acc[i] * dv;
        for (int off = 32; off; off >>= 1) {
            ps += __shfl_xor(ps, off, 64);
            pd += __shfl_xor(pd, off, 64);
        }
        if (lane == 0) {
            as_o[ng * HEADS + head] = ps;
            ad_o[ng * HEADS + head] = pd;
        }
    }
}

// ---------------- GAT aggregation: one wave per (node, head) ---------------
// Lane j computes the softmax weight for edge j (vectorized); den is a wave
// reduction; the serial loop is readlane (SGPR) + saddr row load + fmac.

template <int CT, int HEADS, int ACT>  // ACT: 0 none, 1 elu
__global__ __launch_bounds__(256) void agg_kernel(
    const int* __restrict__ row_ptr, const int* __restrict__ col,
    const float* __restrict__ h, const float* __restrict__ as_,
    const float* __restrict__ ad_, const float* __restrict__ bias,
    float* __restrict__ out, int n) {
    const int gwid = blockIdx.x * 4 + (threadIdx.x >> 6);
    const int lane = threadIdx.x & 63;
    const int node = (HEADS == 2) ? (gwid >> 1) : gwid;
    const int head = (HEADS == 2) ? (gwid & 1) : 0;
    if (node >= n) return;

    const int beg = row_ptr[node], end = row_ptr[node + 1];
    const float adv = ad_[node * HEADS + head];
    const int hoff = head * 64;

    float acc = 0.f, den = 0.f;
    for (int base = beg; base < end; base += 64) {
        int cnt = end - base;
        if (cnt > 64) cnt = 64;
        // vectorized per-edge weight computation: lane j handles edge base+j
        int s = 0;
        float w = 0.f;
        if (lane < cnt) {
            s = col[base + lane];
            float xv = as_[s * HEADS + head] + adv;
            w = __expf(LRELU(xv));
        }
        // denominator: one wave reduction (w==0 on inactive lanes)
        float wsum = w;
        for (int off = 32; off; off >>= 1) wsum += __shfl_xor(wsum, off, 64);
        den += wsum;

        int j = 0;
        for (; j + 3 < cnt; j += 4) {
            int s0 = __builtin_amdgcn_readlane(s, j);
            int s1 = __builtin_amdgcn_readlane(s, j + 1);
            int s2 = __builtin_amdgcn_readlane(s, j + 2);
            int s3 = __builtin_amdgcn_readlane(s, j + 3);
            float w0 = readlane_f(w, j);
            float w1 = readlane_f(w, j + 1);
            float w2 = readlane_f(w, j + 2);
            float w3 = readlane_f(w, j + 3);
            const float* b0 = h + (size_t)s0 * CT + hoff;
            const float* b1 = h + (size_t)s1 * CT + hoff;
            const float* b2 = h + (size_t)s2 * CT + hoff;
            const float* b3 = h + (size_t)s3 * CT + hoff;
            float v0 = b0[lane];
            float v1 = b1[lane];
            float v2 = b2[lane];
            float v3 = b3[lane];
            acc += w0 * v0;
            acc += w1 * v1;
            acc += w2 * v2;
            acc += w3 * v3;
        }
        for (; j < cnt; j++) {
            int s0 = __builtin_amdgcn_readlane(s, j);
            float w0 = readlane_f(w, j);
            acc += w0 * (h + (size_t)s0 * CT + hoff)[lane];
        }
    }

    float o = acc / (den + 1e-16f) + bias[hoff + lane];
    if (ACT) o = o > 0.f ? o : expm1f(o);
    out[(size_t)node * CT + hoff + lane] = o;
}

// ---------------- mean pool over sorted batch ------------------------------

__global__ __launch_bounds__(256) void pool_kernel(
    const float* __restrict__ x, const int* __restrict__ batch,
    float* __restrict__ pooled, float* __restrict__ cnt, int n) {
    const int NPW = 16;
    int wid = blockIdx.x * (blockDim.x >> 6) + (threadIdx.x >> 6);
    int lane = threadIdx.x & 63;
    int start = wid * NPW;
    if (start >= n) return;
    int end = min(start + NPW, n);
    float acc = 0.f, c = 0.f;
    int cur = -1;
    for (int i = start; i < end; i++) {
        int b = batch[i];
        if (b != cur) {
            if (cur >= 0) {
                atomicAdd(&pooled[cur * 64 + lane], acc);
                if (lane == 0) atomicAdd(&cnt[cur], c);
            }
            cur = b;
            acc = 0.f;
            c = 0.f;
        }
        acc += x[(size_t)i * 64 + lane];
        c += 1.f;
    }
    if (cur >= 0) {
        atomicAdd(&pooled[cur * 64 + lane], acc);
        if (lane == 0) atomicAdd(&cnt[cur], c);
    }
}

// ---------------- MLP head: one block per graph row ------------------------

__global__ __launch_bounds__(256) void mlp_kernel(
    const float* __restrict__ pooled, const float* __restrict__ cnt,
    const float* __restrict__ obs,
    const float* __restrict__ Ws1, const float* __restrict__ bs1,
    const float* __restrict__ ln_g, const float* __restrict__ ln_b,
    const float* __restrict__ Ws2, const float* __restrict__ bs2,
    const float* __restrict__ Wa, const float* __restrict__ ba,
    const float* __restrict__ Wc, const float* __restrict__ bc,
    float* __restrict__ out_logits, float* __restrict__ out_value) {
    int b = blockIdx.x;
    int t = threadIdx.x;
    __shared__ float comb[192];
    __shared__ float red[256];
    __shared__ float hs[256];

    if (t < 64) {
        float c = cnt[b];
        c = c > 1.f ? c : 1.f;
        comb[t] = pooled[b * 64 + t] / c;
    } else if (t < 192) {
        comb[t] = obs[b * 128 + (t - 64)];
    }
    __syncthreads();

    float acc = bs1[t];
    for (int k = 0; k < 192; k++) acc += comb[k] * Ws1[k * 256 + t];

    // layernorm over 256 features
    red[t] = acc;
    __syncthreads();
    for (int off = 128; off; off >>= 1) {
        if (t < off) red[t] += red[t + off];
        __syncthreads();
    }
    float mu = red[0] / 256.f;
    __syncthreads();
    float d = acc - mu;
    red[t] = d * d;
    __syncthreads();
    for (int off = 128; off; off >>= 1) {
        if (t < off) red[t] += red[t + off];
        __syncthreads();
    }
    float var = red[0] / 256.f;
    float hn = d * rsqrtf(var + 1e-5f) * ln_g[t] + ln_b[t];
    hn = hn > 0.f ? hn : 0.f;
    __syncthreads();
    hs[t] = hn;
    __syncthreads();

    float acc2 = bs2[t];
    for (int k = 0; k < 256; k++) acc2 += hs[k] * Ws2[k * 256 + t];
    acc2 = acc2 > 0.f ? acc2 : 0.f;
    __syncthreads();
    hs[t] = acc2;
    __syncthreads();

    if (t < 16) {
        float a = ba[t];
        for (int k = 0; k < 256; k++) a += hs[k] * Wa[k * 16 + t];
        out_logits[b * 16 + t] = a;
    } else if (t == 16) {
        float v = bc[0];
        for (int k = 0; k < 256; k++) v += hs[k] * Wc[k];
        out_value[b] = v;
    }
}

// ---------------------------------------------------------------------------

extern "C" void kernel_launch(void* const* d_in, const int* in_sizes, int n_in,
                              void* d_out, int out_size, void* d_ws, size_t ws_size,
                              hipStream_t stream) {
    const float* obs    = (const float*)d_in[0];
    const float* nf     = (const float*)d_in[1];
    const int*   ei     = (const int*)d_in[2];
    const int*   batch  = (const int*)d_in[3];
    const float* W0     = (const float*)d_in[4];
    const float* a_src0 = (const float*)d_in[5];
    const float* a_dst0 = (const float*)d_in[6];
    const float* b0     = (const float*)d_in[7];
    const float* W1     = (const float*)d_in[8];
    const float* a_src1 = (const float*)d_in[9];
    const float* a_dst1 = (const float*)d_in[10];
    const float* b1     = (const float*)d_in[11];
    const float* W2     = (const float*)d_in[12];
    const float* a_src2 = (const float*)d_in[13];
    const float* a_dst2 = (const float*)d_in[14];
    const float* b2     = (const float*)d_in[15];
    const float* Ws1    = (const float*)d_in[16];
    const float* bs1    = (const float*)d_in[17];
    const float* ln_g   = (const float*)d_in[18];
    const float* ln_b   = (const float*)d_in[19];
    const float* Ws2    = (const float*)d_in[20];
    const float* bs2    = (const float*)d_in[21];
    const float* Wa     = (const float*)d_in[22];
    const float* ba     = (const float*)d_in[23];
    const float* Wc     = (const float*)d_in[24];
    const float* bc     = (const float*)d_in[25];

    const int N = in_sizes[3];
    const int E = in_sizes[2] / 2;
    const int B = in_sizes[0] / 128;
    const int* src = ei;
    const int* dstp = ei + E;

    // workspace carve (256B aligned)
    char* p = (char*)d_ws;
    auto alloc = [&](size_t bytes) -> void* {
        void* r = (void*)p;
        p += (bytes + 255) & ~(size_t)255;
        return r;
    };
    int nb = (N + 255) / 256;
    int*   cursor    = (int*)alloc((size_t)N * 4);
    int*   row_ptr   = (int*)alloc((size_t)(N + 1) * 4);
    int*   blockSums = (int*)alloc((size_t)(nb + 1) * 4);
    int*   col       = (int*)alloc((size_t)(E + N) * 4);
    float* hbuf      = (float*)alloc((size_t)N * 128 * 4);
    float* xbuf      = (float*)alloc((size_t)N * 128 * 4);
    float* as_       = (float*)alloc((size_t)N * 2 * 4);
    float* ad_       = (float*)alloc((size_t)N * 2 * 4);
    float* pooled    = (float*)alloc((size_t)(B * 64 + B) * 4);
    float* cnt       = pooled + (size_t)B * 64;

    float* out_logits = (float*)d_out;
    float* out_value  = out_logits + (size_t)B * 16;

    // ---- CSR build (by dst, includes self loops) ----
    init_counts_kernel<<<(N + 255) / 256, 256, 0, stream>>>(cursor, N);
    count_kernel<<<(E + 255) / 256, 256, 0, stream>>>(dstp, cursor, E);
    scan_block_kernel<<<nb, 256, 0, stream>>>(cursor, row_ptr, blockSums, N);
    scan_sums_kernel<<<1, 256, 0, stream>>>(blockSums, nb);
    scan_finalize_kernel<<<(N + 1 + 255) / 256, 256, 0, stream>>>(row_ptr, cursor, blockSums, N, nb);
    scatter_kernel<<<(E + N + 255) / 256, 256, 0, stream>>>(src, dstp, cursor, col, E, N);

    // ---- zero pooled/cnt ----
    hipMemsetAsync(pooled, 0, (size_t)(B * 64 + B) * 4, stream);

    // ---- GAT layer 0: in=8 -> h=[N,2,64] concat, elu ----
    transform_kernel<8, 128, 2><<<(N + 7) / 8, 128, 0, stream>>>(
        nf, W0, a_src0, a_dst0, hbuf, as_, ad_, N);
    agg_kernel<128, 2, 1><<<(2 * N + 3) / 4, 256, 0, stream>>>(
        row_ptr, col, hbuf, as_, ad_, b0, xbuf, N);

    // ---- GAT layer 1: in=128 -> concat, elu ----
    transform_kernel<128, 128, 2><<<(N + 7) / 8, 128, 0, stream>>>(
        xbuf, W1, a_src1, a_dst1, hbuf, as_, ad_, N);
    agg_kernel<128, 2, 1><<<(2 * N + 3) / 4, 256, 0, stream>>>(
        row_ptr, col, hbuf, as_, ad_, b1, xbuf, N);

    // ---- GAT layer 2: in=128 -> heads=1, out=64, no concat, no act ----
    transform_kernel<128, 64, 1><<<(N + 7) / 8, 64, 0, stream>>>(
        xbuf, W2, a_src2, a_dst2, hbuf, as_, ad_, N);
    agg_kernel<64, 1, 0><<<(N + 3) / 4, 256, 0, stream>>>(
        row_ptr, col, hbuf, as_, ad_, b2, xbuf, N);

    // ---- mean pool + MLP head ----
    {
        int waves = (N + 15) / 16;
        int blocks = (waves + 3) / 4;
        pool_kernel<<<blocks, 256, 0, stream>>>(xbuf, batch, pooled, cnt, N);
    }
    mlp_kernel<<<B, 256, 0, stream>>>(pooled, cnt, obs, Ws1, bs1, ln_g, ln_b,
                                      Ws2, bs2, Wa, ba, Wc, bc,
                                      out_logits, out_value);
}

// Round 4
// 452.960 us; speedup vs baseline: 1.4276x; 1.1608x over previous
//
#include <hip/hip_runtime.h>
#include <math.h>

// ---------------------------------------------------------------------------
// GATPolicy: 3x GATConv (with self loops) + mean-pool + MLP head.
// CSR-by-dst built once; aggregation pull-based, one wave per NODE (both
// heads), h stored in bf16 so one uint load per lane carries 2 channels.
// Lanes 0..31 = head0 channels, lanes 32..63 = head1 channels.
// ---------------------------------------------------------------------------

#define LRELU(x) ((x) > 0.f ? (x) : 0.2f * (x))

__device__ __forceinline__ float readlane_f(float v, int lane) {
    return __int_as_float(__builtin_amdgcn_readlane(__float_as_int(v), lane));
}
__device__ __forceinline__ unsigned short f2bf(float f) {
    unsigned int u = __float_as_uint(f);
    u = (u + 0x7fffu + ((u >> 16) & 1u)) >> 16;  // RNE
    return (unsigned short)u;
}
__device__ __forceinline__ float bf_lo(unsigned int u) { return __uint_as_float(u << 16); }
__device__ __forceinline__ float bf_hi(unsigned int u) { return __uint_as_float(u & 0xffff0000u); }

// ---------------- CSR build ----------------

__global__ void init_counts_kernel(int* __restrict__ cursor, int n) {
    int i = blockIdx.x * blockDim.x + threadIdx.x;
    if (i < n) cursor[i] = 1;  // self loop
}

__global__ void count_kernel(const int* __restrict__ dst, int* __restrict__ cursor, int e) {
    int i = blockIdx.x * blockDim.x + threadIdx.x;
    if (i < e) atomicAdd(&cursor[dst[i]], 1);
}

__global__ __launch_bounds__(256) void scan_block_kernel(
    const int* __restrict__ in, int* __restrict__ out_local,
    int* __restrict__ blockSums, int n) {
    __shared__ int lds[256];
    int i = blockIdx.x * 256 + threadIdx.x;
    int v = (i < n) ? in[i] : 0;
    lds[threadIdx.x] = v;
    __syncthreads();
    for (int off = 1; off < 256; off <<= 1) {
        int t = (threadIdx.x >= off) ? lds[threadIdx.x - off] : 0;
        __syncthreads();
        lds[threadIdx.x] += t;
        __syncthreads();
    }
    if (i < n) out_local[i] = lds[threadIdx.x] - v;  // block-local exclusive
    if (threadIdx.x == 255) blockSums[blockIdx.x] = lds[255];
}

__global__ __launch_bounds__(256) void scan_sums_kernel(int* __restrict__ blockSums, int nb) {
    // nb must be <= 256
    __shared__ int lds[256];
    int v = (threadIdx.x < nb) ? blockSums[threadIdx.x] : 0;
    lds[threadIdx.x] = v;
    __syncthreads();
    for (int off = 1; off < 256; off <<= 1) {
        int t = (threadIdx.x >= off) ? lds[threadIdx.x - off] : 0;
        __syncthreads();
        lds[threadIdx.x] += t;
        __syncthreads();
    }
    if (threadIdx.x < nb) blockSums[threadIdx.x] = lds[threadIdx.x] - v;
    if (threadIdx.x == 255) blockSums[nb] = lds[255];  // total
}

__global__ void scan_finalize_kernel(int* __restrict__ row_ptr, int* __restrict__ cursor,
                                     const int* __restrict__ blockSums, int n, int nb) {
    int i = blockIdx.x * blockDim.x + threadIdx.x;
    if (i < n) {
        int v = row_ptr[i] + blockSums[i >> 8];
        row_ptr[i] = v;
        cursor[i] = v;  // write pointer for scatter
    } else if (i == n) {
        row_ptr[n] = blockSums[nb];
    }
}

__global__ void scatter_kernel(const int* __restrict__ src, const int* __restrict__ dst,
                               int* __restrict__ cursor, int* __restrict__ col,
                               int e, int n) {
    int i = blockIdx.x * blockDim.x + threadIdx.x;
    int total = e + n;
    if (i >= total) return;
    int s, d;
    if (i < e) { s = src[i]; d = dst[i]; }
    else       { s = d = i - e; }
    int pos = atomicAdd(&cursor[d], 1);
    col[pos] = s;
}

// ---------------- GAT node transform: h(bf16) = x@W, as/ad fp32 -------------

template <int K, int OUT, int HEADS>
__global__ __launch_bounds__(OUT) void transform_kernel(
    const float* __restrict__ x, const float* __restrict__ W,
    const float* __restrict__ a_src, const float* __restrict__ a_dst,
    unsigned short* __restrict__ h, float* __restrict__ as_o, float* __restrict__ ad_o,
    int n) {
    constexpr int NPB = 8;  // nodes per block (amortizes W reads through L2)
    __shared__ float xs[NPB][K];
    const int tid = threadIdx.x;
    const int node0 = blockIdx.x * NPB;

    for (int idx = tid; idx < NPB * K; idx += OUT) {
        int ni = idx / K, k = idx - ni * K;
        int ng = node0 + ni;
        xs[ni][k] = (ng < n) ? x[(size_t)ng * K + k] : 0.f;
    }
    __syncthreads();

    float acc[NPB];
#pragma unroll
    for (int i = 0; i < NPB; i++) acc[i] = 0.f;
    for (int k = 0; k < K; k++) {
        float wk = W[k * OUT + tid];
#pragma unroll
        for (int i = 0; i < NPB; i++) acc[i] += xs[i][k] * wk;
    }

    const int lane = tid & 63;
    const int head = (HEADS == 2) ? (tid >> 6) : 0;
    const float av = a_src[tid];
    const float dv = a_dst[tid];
#pragma unroll
    for (int i = 0; i < NPB; i++) {
        int ng = node0 + i;
        if (ng >= n) break;  // uniform across block
        h[(size_t)ng * OUT + tid] = f2bf(acc[i]);
        float ps = acc[i] * av, pd = acc[i] * dv;
        for (int off = 32; off; off >>= 1) {
            ps += __shfl_xor(ps, off, 64);
            pd += __shfl_xor(pd, off, 64);
        }
        if (lane == 0) {
            as_o[ng * HEADS + head] = ps;
            ad_o[ng * HEADS + head] = pd;
        }
    }
}

// ---------------- GAT aggregation, 2 heads: one wave per node --------------
// h2: bf16x2 rows of 64 uints (=128 channels). Lane l covers channels
// 2l,2l+1 (l<32 -> head0, l>=32 -> head1). Per edge: 3 readlane + cndmask +
// 1 uint load + 2 unpack + 2 fmac covers BOTH heads.

template <int ACT>  // 1 = elu
__global__ __launch_bounds__(256) void agg2_kernel(
    const int* __restrict__ row_ptr, const int* __restrict__ col,
    const unsigned int* __restrict__ h2, const float2* __restrict__ as2,
    const float2* __restrict__ ad2, const float* __restrict__ bias,
    float* __restrict__ out, int n) {
    const int node = blockIdx.x * 4 + (threadIdx.x >> 6);
    const int lane = threadIdx.x & 63;
    if (node >= n) return;
    const bool hih = lane >= 32;

    const int beg = row_ptr[node], end = row_ptr[node + 1];
    const float2 adv = ad2[node];

    float accL = 0.f, accH = 0.f, den0 = 0.f, den1 = 0.f;
    for (int base = beg; base < end; base += 64) {
        int cnt = end - base;
        if (cnt > 64) cnt = 64;
        int s = 0;
        float w0 = 0.f, w1 = 0.f;
        if (lane < cnt) {
            s = col[base + lane];
            float2 av = as2[s];
            w0 = __expf(LRELU(av.x + adv.x));
            w1 = __expf(LRELU(av.y + adv.y));
        }
        float t0 = w0, t1 = w1;
        for (int off = 32; off; off >>= 1) {
            t0 += __shfl_xor(t0, off, 64);
            t1 += __shfl_xor(t1, off, 64);
        }
        den0 += t0;
        den1 += t1;

        int j = 0;
        for (; j + 3 < cnt; j += 4) {
            int sA = __builtin_amdgcn_readlane(s, j);
            int sB = __builtin_amdgcn_readlane(s, j + 1);
            int sC = __builtin_amdgcn_readlane(s, j + 2);
            int sD = __builtin_amdgcn_readlane(s, j + 3);
            float a0 = readlane_f(w0, j),     a1 = readlane_f(w1, j);
            float b0_ = readlane_f(w0, j + 1), b1_ = readlane_f(w1, j + 1);
            float c0 = readlane_f(w0, j + 2), c1 = readlane_f(w1, j + 2);
            float d0 = readlane_f(w0, j + 3), d1 = readlane_f(w1, j + 3);
            unsigned int uA = h2[(size_t)sA * 64 + lane];
            unsigned int uB = h2[(size_t)sB * 64 + lane];
            unsigned int uC = h2[(size_t)sC * 64 + lane];
            unsigned int uD = h2[(size_t)sD * 64 + lane];
            float wA = hih ? a1 : a0;
            float wB = hih ? b1_ : b0_;
            float wC = hih ? c1 : c0;
            float wD = hih ? d1 : d0;
            accL += wA * bf_lo(uA); accH += wA * bf_hi(uA);
            accL += wB * bf_lo(uB); accH += wB * bf_hi(uB);
            accL += wC * bf_lo(uC); accH += wC * bf_hi(uC);
            accL += wD * bf_lo(uD); accH += wD * bf_hi(uD);
        }
        for (; j < cnt; j++) {
            int sA = __builtin_amdgcn_readlane(s, j);
            float a0 = readlane_f(w0, j), a1 = readlane_f(w1, j);
            float wA = hih ? a1 : a0;
            unsigned int uA = h2[(size_t)sA * 64 + lane];
            accL += wA * bf_lo(uA);
            accH += wA * bf_hi(uA);
        }
    }

    float den = hih ? den1 : den0;
    float inv = 1.f / (den + 1e-16f);
    float2 bv = ((const float2*)bias)[lane];
    float oL = accL * inv + bv.x;
    float oH = accH * inv + bv.y;
    if (ACT) {
        oL = oL > 0.f ? oL : expm1f(oL);
        oH = oH > 0.f ? oH : expm1f(oH);
    }
    ((float2*)out)[(size_t)node * 64 + lane] = make_float2(oL, oH);
}

// ---------------- GAT aggregation, 1 head (layer 2) ------------------------
// h2: bf16x2 rows of 32 uints (=64 channels). Lane halves process two edges
// per iteration; halves combined by shfl_xor(32) at the end.

__global__ __launch_bounds__(256) void agg1_kernel(
    const int* __restrict__ row_ptr, const int* __restrict__ col,
    const unsigned int* __restrict__ h2, const float* __restrict__ as1,
    const float* __restrict__ ad1, const float* __restrict__ bias,
    float* __restrict__ out, int n) {
    const int node = blockIdx.x * 4 + (threadIdx.x >> 6);
    const int lane = threadIdx.x & 63;
    if (node >= n) return;
    const int m = lane & 31;
    const bool hih = lane >= 32;

    const int beg = row_ptr[node], end = row_ptr[node + 1];
    const float adv = ad1[node];

    float accL = 0.f, accH = 0.f, den = 0.f;
    for (int base = beg; base < end; base += 64) {
        int cnt = end - base;
        if (cnt > 64) cnt = 64;
        int s = 0;
        float w = 0.f;
        if (lane < cnt) {
            s = col[base + lane];
            w = __expf(LRELU(as1[s] + adv));
        }
        float t = w;
        for (int off = 32; off; off >>= 1) t += __shfl_xor(t, off, 64);
        den += t;

        int j = 0;
        for (; j + 3 < cnt; j += 4) {
            int sA = __builtin_amdgcn_readlane(s, j);
            int sB = __builtin_amdgcn_readlane(s, j + 1);
            int sC = __builtin_amdgcn_readlane(s, j + 2);
            int sD = __builtin_amdgcn_readlane(s, j + 3);
            float wA = readlane_f(w, j),     wB = readlane_f(w, j + 1);
            float wC = readlane_f(w, j + 2), wD = readlane_f(w, j + 3);
            int s1_ = hih ? sB : sA;
            int s2_ = hih ? sD : sC;
            float w1_ = hih ? wB : wA;
            float w2_ = hih ? wD : wC;
            unsigned int u1 = h2[(size_t)s1_ * 32 + m];
            unsigned int u2 = h2[(size_t)s2_ * 32 + m];
            accL += w1_ * bf_lo(u1); accH += w1_ * bf_hi(u1);
            accL += w2_ * bf_lo(u2); accH += w2_ * bf_hi(u2);
        }
        for (; j < cnt; j += 2) {
            int sA = __builtin_amdgcn_readlane(s, j);
            float wA = readlane_f(w, j);
            int jb = j + 1 < 64 ? j + 1 : 63;
            int sB = __builtin_amdgcn_readlane(s, jb);   // w==0 beyond cnt
            float wB = (j + 1 < cnt) ? readlane_f(w, jb) : 0.f;
            int s1_ = hih ? sB : sA;
            float w1_ = hih ? wB : wA;
            unsigned int u1 = h2[(size_t)s1_ * 32 + m];
            accL += w1_ * bf_lo(u1);
            accH += w1_ * bf_hi(u1);
        }
    }

    accL += __shfl_xor(accL, 32, 64);
    accH += __shfl_xor(accH, 32, 64);
    if (!hih) {
        float inv = 1.f / (den + 1e-16f);
        float2 bv = ((const float2*)bias)[m];
        float oL = accL * inv + bv.x;
        float oH = accH * inv + bv.y;
        ((float2*)out)[(size_t)node * 32 + m] = make_float2(oL, oH);
    }
}

// ---------------- mean pool over sorted batch ------------------------------

__global__ __launch_bounds__(256) void pool_kernel(
    const float* __restrict__ x, const int* __restrict__ batch,
    float* __restrict__ pooled, float* __restrict__ cnt, int n) {
    const int NPW = 16;
    int wid = blockIdx.x * (blockDim.x >> 6) + (threadIdx.x >> 6);
    int lane = threadIdx.x & 63;
    int start = wid * NPW;
    if (start >= n) return;
    int end = min(start + NPW, n);
    float acc = 0.f, c = 0.f;
    int cur = -1;
    for (int i = start; i < end; i++) {
        int b = batch[i];
        if (b != cur) {
            if (cur >= 0) {
                atomicAdd(&pooled[cur * 64 + lane], acc);
                if (lane == 0) atomicAdd(&cnt[cur], c);
            }
            cur = b;
            acc = 0.f;
            c = 0.f;
        }
        acc += x[(size_t)i * 64 + lane];
        c += 1.f;
    }
    if (cur >= 0) {
        atomicAdd(&pooled[cur * 64 + lane], acc);
        if (lane == 0) atomicAdd(&cnt[cur], c);
    }
}

// ---------------- MLP head: one block per graph row ------------------------

__global__ __launch_bounds__(256) void mlp_kernel(
    const float* __restrict__ pooled, const float* __restrict__ cnt,
    const float* __restrict__ obs,
    const float* __restrict__ Ws1, const float* __restrict__ bs1,
    const float* __restrict__ ln_g, const float* __restrict__ ln_b,
    const float* __restrict__ Ws2, const float* __restrict__ bs2,
    const float* __restrict__ Wa, const float* __restrict__ ba,
    const float* __restrict__ Wc, const float* __restrict__ bc,
    float* __restrict__ out_logits, float* __restrict__ out_value) {
    int b = blockIdx.x;
    int t = threadIdx.x;
    __shared__ float comb[192];
    __shared__ float red[256];
    __shared__ float hs[256];

    if (t < 64) {
        float c = cnt[b];
        c = c > 1.f ? c : 1.f;
        comb[t] = pooled[b * 64 + t] / c;
    } else if (t < 192) {
        comb[t] = obs[b * 128 + (t - 64)];
    }
    __syncthreads();

    float acc = bs1[t];
    for (int k = 0; k < 192; k++) acc += comb[k] * Ws1[k * 256 + t];

    // layernorm over 256 features
    red[t] = acc;
    __syncthreads();
    for (int off = 128; off; off >>= 1) {
        if (t < off) red[t] += red[t + off];
        __syncthreads();
    }
    float mu = red[0] / 256.f;
    __syncthreads();
    float d = acc - mu;
    red[t] = d * d;
    __syncthreads();
    for (int off = 128; off; off >>= 1) {
        if (t < off) red[t] += red[t + off];
        __syncthreads();
    }
    float var = red[0] / 256.f;
    float hn = d * rsqrtf(var + 1e-5f) * ln_g[t] + ln_b[t];
    hn = hn > 0.f ? hn : 0.f;
    __syncthreads();
    hs[t] = hn;
    __syncthreads();

    float acc2 = bs2[t];
    for (int k = 0; k < 256; k++) acc2 += hs[k] * Ws2[k * 256 + t];
    acc2 = acc2 > 0.f ? acc2 : 0.f;
    __syncthreads();
    hs[t] = acc2;
    __syncthreads();

    if (t < 16) {
        float a = ba[t];
        for (int k = 0; k < 256; k++) a += hs[k] * Wa[k * 16 + t];
        out_logits[b * 16 + t] = a;
    } else if (t == 16) {
        float v = bc[0];
        for (int k = 0; k < 256; k++) v += hs[k] * Wc[k];
        out_value[b] = v;
    }
}

// ---------------------------------------------------------------------------

extern "C" void kernel_launch(void* const* d_in, const int* in_sizes, int n_in,
                              void* d_out, int out_size, void* d_ws, size_t ws_size,
                              hipStream_t stream) {
    const float* obs    = (const float*)d_in[0];
    const float* nf     = (const float*)d_in[1];
    const int*   ei     = (const int*)d_in[2];
    const int*   batch  = (const int*)d_in[3];
    const float* W0     = (const float*)d_in[4];
    const float* a_src0 = (const float*)d_in[5];
    const float* a_dst0 = (const float*)d_in[6];
    const float* b0     = (const float*)d_in[7];
    const float* W1     = (const float*)d_in[8];
    const float* a_src1 = (const float*)d_in[9];
    const float* a_dst1 = (const float*)d_in[10];
    const float* b1     = (const float*)d_in[11];
    const float* W2     = (const float*)d_in[12];
    const float* a_src2 = (const float*)d_in[13];
    const float* a_dst2 = (const float*)d_in[14];
    const float* b2     = (const float*)d_in[15];
    const float* Ws1    = (const float*)d_in[16];
    const float* bs1    = (const float*)d_in[17];
    const float* ln_g   = (const float*)d_in[18];
    const float* ln_b   = (const float*)d_in[19];
    const float* Ws2    = (const float*)d_in[20];
    const float* bs2    = (const float*)d_in[21];
    const float* Wa     = (const float*)d_in[22];
    const float* ba     = (const float*)d_in[23];
    const float* Wc     = (const float*)d_in[24];
    const float* bc     = (const float*)d_in[25];

    const int N = in_sizes[3];
    const int E = in_sizes[2] / 2;
    const int B = in_sizes[0] / 128;
    const int* src = ei;
    const int* dstp = ei + E;

    // workspace carve (256B aligned)
    char* p = (char*)d_ws;
    auto alloc = [&](size_t bytes) -> void* {
        void* r = (void*)p;
        p += (bytes + 255) & ~(size_t)255;
        return r;
    };
    int nb = (N + 255) / 256;
    int*   cursor    = (int*)alloc((size_t)N * 4);
    int*   row_ptr   = (int*)alloc((size_t)(N + 1) * 4);
    int*   blockSums = (int*)alloc((size_t)(nb + 1) * 4);
    int*   col       = (int*)alloc((size_t)(E + N) * 4);
    unsigned short* hbuf = (unsigned short*)alloc((size_t)N * 128 * 2);  // bf16
    float* xbuf      = (float*)alloc((size_t)N * 128 * 4);
    float* as_       = (float*)alloc((size_t)N * 2 * 4);
    float* ad_       = (float*)alloc((size_t)N * 2 * 4);
    float* pooled    = (float*)alloc((size_t)(B * 64 + B) * 4);
    float* cnt       = pooled + (size_t)B * 64;

    float* out_logits = (float*)d_out;
    float* out_value  = out_logits + (size_t)B * 16;

    // ---- CSR build (by dst, includes self loops) ----
    init_counts_kernel<<<(N + 255) / 256, 256, 0, stream>>>(cursor, N);
    count_kernel<<<(E + 255) / 256, 256, 0, stream>>>(dstp, cursor, E);
    scan_block_kernel<<<nb, 256, 0, stream>>>(cursor, row_ptr, blockSums, N);
    scan_sums_kernel<<<1, 256, 0, stream>>>(blockSums, nb);
    scan_finalize_kernel<<<(N + 1 + 255) / 256, 256, 0, stream>>>(row_ptr, cursor, blockSums, N, nb);
    scatter_kernel<<<(E + N + 255) / 256, 256, 0, stream>>>(src, dstp, cursor, col, E, N);

    // ---- zero pooled/cnt ----
    hipMemsetAsync(pooled, 0, (size_t)(B * 64 + B) * 4, stream);

    // ---- GAT layer 0: in=8 -> h=[N,2,64] concat, elu ----
    transform_kernel<8, 128, 2><<<(N + 7) / 8, 128, 0, stream>>>(
        nf, W0, a_src0, a_dst0, hbuf, as_, ad_, N);
    agg2_kernel<1><<<(N + 3) / 4, 256, 0, stream>>>(
        row_ptr, col, (const unsigned int*)hbuf, (const float2*)as_,
        (const float2*)ad_, b0, xbuf, N);

    // ---- GAT layer 1: in=128 -> concat, elu ----
    transform_kernel<128, 128, 2><<<(N + 7) / 8, 128, 0, stream>>>(
        xbuf, W1, a_src1, a_dst1, hbuf, as_, ad_, N);
    agg2_kernel<1><<<(N + 3) / 4, 256, 0, stream>>>(
        row_ptr, col, (const unsigned int*)hbuf, (const float2*)as_,
        (const float2*)ad_, b1, xbuf, N);

    // ---- GAT layer 2: in=128 -> heads=1, out=64, no concat, no act ----
    transform_kernel<128, 64, 1><<<(N + 7) / 8, 64, 0, stream>>>(
        xbuf, W2, a_src2, a_dst2, hbuf, as_, ad_, N);
    agg1_kernel<<<(N + 3) / 4, 256, 0, stream>>>(
        row_ptr, col, (const unsigned int*)hbuf, as_, ad_, b2, xbuf, N);

    // ---- mean pool + MLP head ----
    {
        int waves = (N + 15) / 16;
        int blocks = (waves + 3) / 4;
        pool_kernel<<<blocks, 256, 0, stream>>>(xbuf, batch, pooled, cnt, N);
    }
    mlp_kernel<<<B, 256, 0, stream>>>(pooled, cnt, obs, Ws1, bs1, ln_g, ln_b,
                                      Ws2, bs2, Wa, ba, Wc, bc,
                                      out_logits, out_value);
}

// Round 5
// 449.064 us; speedup vs baseline: 1.4400x; 1.0087x over previous
//
#include <hip/hip_runtime.h>
#include <math.h>

// ---------------------------------------------------------------------------
// GATPolicy: 3x GATConv (with self loops) + mean-pool + MLP head.
// CSR-by-dst (real edges only; self-loops handled implicitly in agg) built
// once per call with ILP-batched latency-bound passes. Aggregation pull-based,
// one wave per node, h stored bf16 (one uint load carries 2 channels).
// ---------------------------------------------------------------------------

#define LRELU(x) ((x) > 0.f ? (x) : 0.2f * (x))

__device__ __forceinline__ float readlane_f(float v, int lane) {
    return __int_as_float(__builtin_amdgcn_readlane(__float_as_int(v), lane));
}
__device__ __forceinline__ unsigned short f2bf(float f) {
    unsigned int u = __float_as_uint(f);
    u = (u + 0x7fffu + ((u >> 16) & 1u)) >> 16;  // RNE
    return (unsigned short)u;
}
__device__ __forceinline__ float bf_lo(unsigned int u) { return __uint_as_float(u << 16); }
__device__ __forceinline__ float bf_hi(unsigned int u) { return __uint_as_float(u & 0xffff0000u); }

// ---------------- CSR build (ILP-batched) ----------------

// Each thread handles 8 edges spaced by total-thread-count: 8 independent
// loads in flight, then 8 independent atomics.
__global__ __launch_bounds__(256) void count_kernel(
    const int* __restrict__ dst, int* __restrict__ cursor, int e, int T) {
    int i0 = blockIdx.x * 256 + threadIdx.x;
    int d[8];
#pragma unroll
    for (int j = 0; j < 8; j++) {
        int ij = i0 + j * T;
        d[j] = (ij < e) ? dst[ij] : -1;
    }
#pragma unroll
    for (int j = 0; j < 8; j++) {
        if (d[j] >= 0) atomicAdd(&cursor[d[j]], 1);
    }
}

__global__ __launch_bounds__(256) void scan_block_kernel(
    const int* __restrict__ in, int* __restrict__ out_local,
    int* __restrict__ blockSums, int n) {
    __shared__ int lds[256];
    int i = blockIdx.x * 256 + threadIdx.x;
    int v = (i < n) ? in[i] : 0;
    lds[threadIdx.x] = v;
    __syncthreads();
    for (int off = 1; off < 256; off <<= 1) {
        int t = (threadIdx.x >= off) ? lds[threadIdx.x - off] : 0;
        __syncthreads();
        lds[threadIdx.x] += t;
        __syncthreads();
    }
    if (i < n) out_local[i] = lds[threadIdx.x] - v;  // block-local exclusive
    if (threadIdx.x == 255) blockSums[blockIdx.x] = lds[255];
}

__global__ __launch_bounds__(256) void scan_sums_kernel(int* __restrict__ blockSums, int nb) {
    // nb must be <= 256
    __shared__ int lds[256];
    int v = (threadIdx.x < nb) ? blockSums[threadIdx.x] : 0;
    lds[threadIdx.x] = v;
    __syncthreads();
    for (int off = 1; off < 256; off <<= 1) {
        int t = (threadIdx.x >= off) ? lds[threadIdx.x - off] : 0;
        __syncthreads();
        lds[threadIdx.x] += t;
        __syncthreads();
    }
    if (threadIdx.x < nb) blockSums[threadIdx.x] = lds[threadIdx.x] - v;
    if (threadIdx.x == 255) blockSums[nb] = lds[255];  // total
}

__global__ void scan_finalize_kernel(int* __restrict__ row_ptr, int* __restrict__ cursor,
                                     const int* __restrict__ blockSums, int n, int nb) {
    int i = blockIdx.x * blockDim.x + threadIdx.x;
    if (i < n) {
        int v = row_ptr[i] + blockSums[i >> 8];
        row_ptr[i] = v;
        cursor[i] = v;  // write pointer for scatter
    } else if (i == n) {
        row_ptr[n] = blockSums[nb];
    }
}

// Each thread handles 4 edges: 8 independent loads, 4 independent atomics,
// 4 independent stores — latency chains overlap.
__global__ __launch_bounds__(256) void scatter_kernel(
    const int* __restrict__ src, const int* __restrict__ dst,
    int* __restrict__ cursor, int* __restrict__ col, int e, int T) {
    int i0 = blockIdx.x * 256 + threadIdx.x;
    int s[4], d[4];
#pragma unroll
    for (int j = 0; j < 4; j++) {
        int ij = i0 + j * T;
        bool v = ij < e;
        s[j] = v ? src[ij] : 0;
        d[j] = v ? dst[ij] : -1;
    }
    int p[4];
#pragma unroll
    for (int j = 0; j < 4; j++) {
        p[j] = (d[j] >= 0) ? atomicAdd(&cursor[d[j]], 1) : 0;
    }
#pragma unroll
    for (int j = 0; j < 4; j++) {
        if (d[j] >= 0) col[p[j]] = s[j];
    }
}

// ---------------- GAT node transform: h(bf16) = x@W, as/ad fp32 -------------

template <int K, int OUT, int HEADS>
__global__ __launch_bounds__(OUT) void transform_kernel(
    const float* __restrict__ x, const float* __restrict__ W,
    const float* __restrict__ a_src, const float* __restrict__ a_dst,
    unsigned short* __restrict__ h, float* __restrict__ as_o, float* __restrict__ ad_o,
    int n) {
    constexpr int NPB = 8;  // nodes per block (amortizes W reads through L2)
    __shared__ float xs[NPB][K];
    const int tid = threadIdx.x;
    const int node0 = blockIdx.x * NPB;

    for (int idx = tid; idx < NPB * K; idx += OUT) {
        int ni = idx / K, k = idx - ni * K;
        int ng = node0 + ni;
        xs[ni][k] = (ng < n) ? x[(size_t)ng * K + k] : 0.f;
    }
    __syncthreads();

    float acc[NPB];
#pragma unroll
    for (int i = 0; i < NPB; i++) acc[i] = 0.f;
    for (int k = 0; k < K; k++) {
        float wk = W[k * OUT + tid];
#pragma unroll
        for (int i = 0; i < NPB; i++) acc[i] += xs[i][k] * wk;
    }

    const int lane = tid & 63;
    const int head = (HEADS == 2) ? (tid >> 6) : 0;
    const float av = a_src[tid];
    const float dv = a_dst[tid];
#pragma unroll
    for (int i = 0; i < NPB; i++) {
        int ng = node0 + i;
        if (ng >= n) break;  // uniform across block
        h[(size_t)ng * OUT + tid] = f2bf(acc[i]);
        float ps = acc[i] * av, pd = acc[i] * dv;
        for (int off = 32; off; off >>= 1) {
            ps += __shfl_xor(ps, off, 64);
            pd += __shfl_xor(pd, off, 64);
        }
        if (lane == 0) {
            as_o[ng * HEADS + head] = ps;
            ad_o[ng * HEADS + head] = pd;
        }
    }
}

// ---------------- GAT aggregation, 2 heads: one wave per node --------------
// Self-loop handled implicitly (den/acc initialized from node's own row).

template <int ACT>  // 1 = elu
__global__ __launch_bounds__(256) void agg2_kernel(
    const int* __restrict__ row_ptr, const int* __restrict__ col,
    const unsigned int* __restrict__ h2, const float2* __restrict__ as2,
    const float2* __restrict__ ad2, const float* __restrict__ bias,
    float* __restrict__ out, int n) {
    const int node = blockIdx.x * 4 + (threadIdx.x >> 6);
    const int lane = threadIdx.x & 63;
    if (node >= n) return;
    const bool hih = lane >= 32;

    const int beg = row_ptr[node], end = row_ptr[node + 1];
    const float2 adv = ad2[node];

    // self-loop contribution
    const float2 avs = as2[node];
    float w0s = __expf(LRELU(avs.x + adv.x));
    float w1s = __expf(LRELU(avs.y + adv.y));
    unsigned int us = h2[(size_t)node * 64 + lane];
    float wS = hih ? w1s : w0s;
    float accL = wS * bf_lo(us), accH = wS * bf_hi(us);
    float den0 = w0s, den1 = w1s;

    for (int base = beg; base < end; base += 64) {
        int cnt = end - base;
        if (cnt > 64) cnt = 64;
        int s = 0;
        float w0 = 0.f, w1 = 0.f;
        if (lane < cnt) {
            s = col[base + lane];
            float2 av = as2[s];
            w0 = __expf(LRELU(av.x + adv.x));
            w1 = __expf(LRELU(av.y + adv.y));
        }
        float t0 = w0, t1 = w1;
        for (int off = 32; off; off >>= 1) {
            t0 += __shfl_xor(t0, off, 64);
            t1 += __shfl_xor(t1, off, 64);
        }
        den0 += t0;
        den1 += t1;

        int j = 0;
        for (; j + 3 < cnt; j += 4) {
            int sA = __builtin_amdgcn_readlane(s, j);
            int sB = __builtin_amdgcn_readlane(s, j + 1);
            int sC = __builtin_amdgcn_readlane(s, j + 2);
            int sD = __builtin_amdgcn_readlane(s, j + 3);
            float a0 = readlane_f(w0, j),     a1 = readlane_f(w1, j);
            float b0_ = readlane_f(w0, j + 1), b1_ = readlane_f(w1, j + 1);
            float c0 = readlane_f(w0, j + 2), c1 = readlane_f(w1, j + 2);
            float d0 = readlane_f(w0, j + 3), d1 = readlane_f(w1, j + 3);
            unsigned int uA = h2[(size_t)sA * 64 + lane];
            unsigned int uB = h2[(size_t)sB * 64 + lane];
            unsigned int uC = h2[(size_t)sC * 64 + lane];
            unsigned int uD = h2[(size_t)sD * 64 + lane];
            float wA = hih ? a1 : a0;
            float wB = hih ? b1_ : b0_;
            float wC = hih ? c1 : c0;
            float wD = hih ? d1 : d0;
            accL += wA * bf_lo(uA); accH += wA * bf_hi(uA);
            accL += wB * bf_lo(uB); accH += wB * bf_hi(uB);
            accL += wC * bf_lo(uC); accH += wC * bf_hi(uC);
            accL += wD * bf_lo(uD); accH += wD * bf_hi(uD);
        }
        for (; j < cnt; j++) {
            int sA = __builtin_amdgcn_readlane(s, j);
            float a0 = readlane_f(w0, j), a1 = readlane_f(w1, j);
            float wA = hih ? a1 : a0;
            unsigned int uA = h2[(size_t)sA * 64 + lane];
            accL += wA * bf_lo(uA);
            accH += wA * bf_hi(uA);
        }
    }

    float den = hih ? den1 : den0;
    float inv = 1.f / (den + 1e-16f);
    float2 bv = ((const float2*)bias)[lane];
    float oL = accL * inv + bv.x;
    float oH = accH * inv + bv.y;
    if (ACT) {
        oL = oL > 0.f ? oL : expm1f(oL);
        oH = oH > 0.f ? oH : expm1f(oH);
    }
    ((float2*)out)[(size_t)node * 64 + lane] = make_float2(oL, oH);
}

// ---------------- GAT aggregation, 1 head (layer 2) ------------------------

__global__ __launch_bounds__(256) void agg1_kernel(
    const int* __restrict__ row_ptr, const int* __restrict__ col,
    const unsigned int* __restrict__ h2, const float* __restrict__ as1,
    const float* __restrict__ ad1, const float* __restrict__ bias,
    float* __restrict__ out, int n) {
    const int node = blockIdx.x * 4 + (threadIdx.x >> 6);
    const int lane = threadIdx.x & 63;
    if (node >= n) return;
    const int m = lane & 31;
    const bool hih = lane >= 32;

    const int beg = row_ptr[node], end = row_ptr[node + 1];
    const float adv = ad1[node];

    // self-loop contribution (added in low half only; halves are summed later)
    float ws = __expf(LRELU(as1[node] + adv));
    float den = ws;
    float accL = 0.f, accH = 0.f;
    {
        unsigned int u = h2[(size_t)node * 32 + m];
        if (!hih) {
            accL = ws * bf_lo(u);
            accH = ws * bf_hi(u);
        }
    }

    for (int base = beg; base < end; base += 64) {
        int cnt = end - base;
        if (cnt > 64) cnt = 64;
        int s = 0;
        float w = 0.f;
        if (lane < cnt) {
            s = col[base + lane];
            w = __expf(LRELU(as1[s] + adv));
        }
        float t = w;
        for (int off = 32; off; off >>= 1) t += __shfl_xor(t, off, 64);
        den += t;

        int j = 0;
        for (; j + 3 < cnt; j += 4) {
            int sA = __builtin_amdgcn_readlane(s, j);
            int sB = __builtin_amdgcn_readlane(s, j + 1);
            int sC = __builtin_amdgcn_readlane(s, j + 2);
            int sD = __builtin_amdgcn_readlane(s, j + 3);
            float wA = readlane_f(w, j),     wB = readlane_f(w, j + 1);
            float wC = readlane_f(w, j + 2), wD = readlane_f(w, j + 3);
            int s1_ = hih ? sB : sA;
            int s2_ = hih ? sD : sC;
            float w1_ = hih ? wB : wA;
            float w2_ = hih ? wD : wC;
            unsigned int u1 = h2[(size_t)s1_ * 32 + m];
            unsigned int u2 = h2[(size_t)s2_ * 32 + m];
            accL += w1_ * bf_lo(u1); accH += w1_ * bf_hi(u1);
            accL += w2_ * bf_lo(u2); accH += w2_ * bf_hi(u2);
        }
        for (; j < cnt; j += 2) {
            int sA = __builtin_amdgcn_readlane(s, j);
            float wA = readlane_f(w, j);
            int jb = j + 1 < 64 ? j + 1 : 63;
            int sB = __builtin_amdgcn_readlane(s, jb);   // w==0 beyond cnt
            float wB = (j + 1 < cnt) ? readlane_f(w, jb) : 0.f;
            int s1_ = hih ? sB : sA;
            float w1_ = hih ? wB : wA;
            unsigned int u1 = h2[(size_t)s1_ * 32 + m];
            accL += w1_ * bf_lo(u1);
            accH += w1_ * bf_hi(u1);
        }
    }

    accL += __shfl_xor(accL, 32, 64);
    accH += __shfl_xor(accH, 32, 64);
    if (!hih) {
        float inv = 1.f / (den + 1e-16f);
        float2 bv = ((const float2*)bias)[m];
        float oL = accL * inv + bv.x;
        float oH = accH * inv + bv.y;
        ((float2*)out)[(size_t)node * 32 + m] = make_float2(oL, oH);
    }
}

// ---------------- mean pool over sorted batch ------------------------------

__global__ __launch_bounds__(256) void pool_kernel(
    const float* __restrict__ x, const int* __restrict__ batch,
    float* __restrict__ pooled, float* __restrict__ cnt, int n) {
    const int NPW = 16;
    int wid = blockIdx.x * (blockDim.x >> 6) + (threadIdx.x >> 6);
    int lane = threadIdx.x & 63;
    int start = wid * NPW;
    if (start >= n) return;
    int end = min(start + NPW, n);
    float acc = 0.f, c = 0.f;
    int cur = -1;
    for (int i = start; i < end; i++) {
        int b = batch[i];
        if (b != cur) {
            if (cur >= 0) {
                atomicAdd(&pooled[cur * 64 + lane], acc);
                if (lane == 0) atomicAdd(&cnt[cur], c);
            }
            cur = b;
            acc = 0.f;
            c = 0.f;
        }
        acc += x[(size_t)i * 64 + lane];
        c += 1.f;
    }
    if (cur >= 0) {
        atomicAdd(&pooled[cur * 64 + lane], acc);
        if (lane == 0) atomicAdd(&cnt[cur], c);
    }
}

// ---------------- MLP head: one block per graph row ------------------------

__global__ __launch_bounds__(256) void mlp_kernel(
    const float* __restrict__ pooled, const float* __restrict__ cnt,
    const float* __restrict__ obs,
    const float* __restrict__ Ws1, const float* __restrict__ bs1,
    const float* __restrict__ ln_g, const float* __restrict__ ln_b,
    const float* __restrict__ Ws2, const float* __restrict__ bs2,
    const float* __restrict__ Wa, const float* __restrict__ ba,
    const float* __restrict__ Wc, const float* __restrict__ bc,
    float* __restrict__ out_logits, float* __restrict__ out_value) {
    int b = blockIdx.x;
    int t = threadIdx.x;
    __shared__ float comb[192];
    __shared__ float red[256];
    __shared__ float hs[256];

    if (t < 64) {
        float c = cnt[b];
        c = c > 1.f ? c : 1.f;
        comb[t] = pooled[b * 64 + t] / c;
    } else if (t < 192) {
        comb[t] = obs[b * 128 + (t - 64)];
    }
    __syncthreads();

    float acc = bs1[t];
    for (int k = 0; k < 192; k++) acc += comb[k] * Ws1[k * 256 + t];

    // layernorm over 256 features
    red[t] = acc;
    __syncthreads();
    for (int off = 128; off; off >>= 1) {
        if (t < off) red[t] += red[t + off];
        __syncthreads();
    }
    float mu = red[0] / 256.f;
    __syncthreads();
    float d = acc - mu;
    red[t] = d * d;
    __syncthreads();
    for (int off = 128; off; off >>= 1) {
        if (t < off) red[t] += red[t + off];
        __syncthreads();
    }
    float var = red[0] / 256.f;
    float hn = d * rsqrtf(var + 1e-5f) * ln_g[t] + ln_b[t];
    hn = hn > 0.f ? hn : 0.f;
    __syncthreads();
    hs[t] = hn;
    __syncthreads();

    float acc2 = bs2[t];
    for (int k = 0; k < 256; k++) acc2 += hs[k] * Ws2[k * 256 + t];
    acc2 = acc2 > 0.f ? acc2 : 0.f;
    __syncthreads();
    hs[t] = acc2;
    __syncthreads();

    if (t < 16) {
        float a = ba[t];
        for (int k = 0; k < 256; k++) a += hs[k] * Wa[k * 16 + t];
        out_logits[b * 16 + t] = a;
    } else if (t == 16) {
        float v = bc[0];
        for (int k = 0; k < 256; k++) v += hs[k] * Wc[k];
        out_value[b] = v;
    }
}

// ---------------------------------------------------------------------------

extern "C" void kernel_launch(void* const* d_in, const int* in_sizes, int n_in,
                              void* d_out, int out_size, void* d_ws, size_t ws_size,
                              hipStream_t stream) {
    const float* obs    = (const float*)d_in[0];
    const float* nf     = (const float*)d_in[1];
    const int*   ei     = (const int*)d_in[2];
    const int*   batch  = (const int*)d_in[3];
    const float* W0     = (const float*)d_in[4];
    const float* a_src0 = (const float*)d_in[5];
    const float* a_dst0 = (const float*)d_in[6];
    const float* b0     = (const float*)d_in[7];
    const float* W1     = (const float*)d_in[8];
    const float* a_src1 = (const float*)d_in[9];
    const float* a_dst1 = (const float*)d_in[10];
    const float* b1     = (const float*)d_in[11];
    const float* W2     = (const float*)d_in[12];
    const float* a_src2 = (const float*)d_in[13];
    const float* a_dst2 = (const float*)d_in[14];
    const float* b2     = (const float*)d_in[15];
    const float* Ws1    = (const float*)d_in[16];
    const float* bs1    = (const float*)d_in[17];
    const float* ln_g   = (const float*)d_in[18];
    const float* ln_b   = (const float*)d_in[19];
    const float* Ws2    = (const float*)d_in[20];
    const float* bs2    = (const float*)d_in[21];
    const float* Wa     = (const float*)d_in[22];
    const float* ba     = (const float*)d_in[23];
    const float* Wc     = (const float*)d_in[24];
    const float* bc     = (const float*)d_in[25];

    const int N = in_sizes[3];
    const int E = in_sizes[2] / 2;
    const int B = in_sizes[0] / 128;
    const int* src = ei;
    const int* dstp = ei + E;

    // workspace carve (256B aligned)
    char* p = (char*)d_ws;
    auto alloc = [&](size_t bytes) -> void* {
        void* r = (void*)p;
        p += (bytes + 255) & ~(size_t)255;
        return r;
    };
    int nb = (N + 255) / 256;
    int*   cursor    = (int*)alloc((size_t)N * 4);
    int*   row_ptr   = (int*)alloc((size_t)(N + 1) * 4);
    int*   blockSums = (int*)alloc((size_t)(nb + 1) * 4);
    int*   col       = (int*)alloc((size_t)E * 4);
    unsigned short* hbuf = (unsigned short*)alloc((size_t)N * 128 * 2);  // bf16
    float* xbuf      = (float*)alloc((size_t)N * 128 * 4);
    float* as_       = (float*)alloc((size_t)N * 2 * 4);
    float* ad_       = (float*)alloc((size_t)N * 2 * 4);
    float* pooled    = (float*)alloc((size_t)(B * 64 + B) * 4);
    float* cnt       = pooled + (size_t)B * 64;

    float* out_logits = (float*)d_out;
    float* out_value  = out_logits + (size_t)B * 16;

    // ---- CSR build (by dst, real edges only; self-loops implicit in agg) ----
    hipMemsetAsync(cursor, 0, (size_t)N * 4, stream);
    {
        int blocks = (E + 8 * 256 - 1) / (8 * 256);
        int T = blocks * 256;
        count_kernel<<<blocks, 256, 0, stream>>>(dstp, cursor, E, T);
    }
    scan_block_kernel<<<nb, 256, 0, stream>>>(cursor, row_ptr, blockSums, N);
    scan_sums_kernel<<<1, 256, 0, stream>>>(blockSums, nb);
    scan_finalize_kernel<<<(N + 1 + 255) / 256, 256, 0, stream>>>(row_ptr, cursor, blockSums, N, nb);
    {
        int blocks = (E + 4 * 256 - 1) / (4 * 256);
        int T = blocks * 256;
        scatter_kernel<<<blocks, 256, 0, stream>>>(src, dstp, cursor, col, E, T);
    }

    // ---- zero pooled/cnt ----
    hipMemsetAsync(pooled, 0, (size_t)(B * 64 + B) * 4, stream);

    // ---- GAT layer 0: in=8 -> h=[N,2,64] concat, elu ----
    transform_kernel<8, 128, 2><<<(N + 7) / 8, 128, 0, stream>>>(
        nf, W0, a_src0, a_dst0, hbuf, as_, ad_, N);
    agg2_kernel<1><<<(N + 3) / 4, 256, 0, stream>>>(
        row_ptr, col, (const unsigned int*)hbuf, (const float2*)as_,
        (const float2*)ad_, b0, xbuf, N);

    // ---- GAT layer 1: in=128 -> concat, elu ----
    transform_kernel<128, 128, 2><<<(N + 7) / 8, 128, 0, stream>>>(
        xbuf, W1, a_src1, a_dst1, hbuf, as_, ad_, N);
    agg2_kernel<1><<<(N + 3) / 4, 256, 0, stream>>>(
        row_ptr, col, (const unsigned int*)hbuf, (const float2*)as_,
        (const float2*)ad_, b1, xbuf, N);

    // ---- GAT layer 2: in=128 -> heads=1, out=64, no concat, no act ----
    transform_kernel<128, 64, 1><<<(N + 7) / 8, 64, 0, stream>>>(
        xbuf, W2, a_src2, a_dst2, hbuf, as_, ad_, N);
    agg1_kernel<<<(N + 3) / 4, 256, 0, stream>>>(
        row_ptr, col, (const unsigned int*)hbuf, as_, ad_, b2, xbuf, N);

    // ---- mean pool + MLP head ----
    {
        int waves = (N + 15) / 16;
        int blocks = (waves + 3) / 4;
        pool_kernel<<<blocks, 256, 0, stream>>>(xbuf, batch, pooled, cnt, N);
    }
    mlp_kernel<<<B, 256, 0, stream>>>(pooled, cnt, obs, Ws1, bs1, ln_g, ln_b,
                                      Ws2, bs2, Wa, ba, Wc, bc,
                                      out_logits, out_value);
}

// Round 6
// 405.697 us; speedup vs baseline: 1.5939x; 1.1069x over previous
//
#include <hip/hip_runtime.h>
#include <math.h>

// ---------------------------------------------------------------------------
// GATPolicy: 3x GATConv (with self loops) + mean-pool + MLP head.
// CSR-by-dst (real edges only; self-loops implicit in agg). Inter-layer node
// features stored bf16; K=128 transforms use mfma_f32_16x16x32_bf16 with
// pre-packed W fragments. Aggregation pull-based, one wave per node.
// ---------------------------------------------------------------------------

#define LRELU(x) ((x) > 0.f ? (x) : 0.2f * (x))

typedef short bf16x8 __attribute__((ext_vector_type(8)));
typedef float f32x4 __attribute__((ext_vector_type(4)));

__device__ __forceinline__ float readlane_f(float v, int lane) {
    return __int_as_float(__builtin_amdgcn_readlane(__float_as_int(v), lane));
}
__device__ __forceinline__ unsigned short f2bf(float f) {
    unsigned int u = __float_as_uint(f);
    u = (u + 0x7fffu + ((u >> 16) & 1u)) >> 16;  // RNE
    return (unsigned short)u;
}
__device__ __forceinline__ float bf_lo(unsigned int u) { return __uint_as_float(u << 16); }
__device__ __forceinline__ float bf_hi(unsigned int u) { return __uint_as_float(u & 0xffff0000u); }

// ---------------- CSR build (ILP-batched) ----------------

__global__ __launch_bounds__(256) void count_kernel(
    const int* __restrict__ dst, int* __restrict__ cursor, int e, int T) {
    int i0 = blockIdx.x * 256 + threadIdx.x;
    int d[8];
#pragma unroll
    for (int j = 0; j < 8; j++) {
        int ij = i0 + j * T;
        d[j] = (ij < e) ? dst[ij] : -1;
    }
#pragma unroll
    for (int j = 0; j < 8; j++) {
        if (d[j] >= 0) atomicAdd(&cursor[d[j]], 1);
    }
}

__global__ __launch_bounds__(256) void scan_block_kernel(
    const int* __restrict__ in, int* __restrict__ out_local,
    int* __restrict__ blockSums, int n) {
    __shared__ int lds[256];
    int i = blockIdx.x * 256 + threadIdx.x;
    int v = (i < n) ? in[i] : 0;
    lds[threadIdx.x] = v;
    __syncthreads();
    for (int off = 1; off < 256; off <<= 1) {
        int t = (threadIdx.x >= off) ? lds[threadIdx.x - off] : 0;
        __syncthreads();
        lds[threadIdx.x] += t;
        __syncthreads();
    }
    if (i < n) out_local[i] = lds[threadIdx.x] - v;  // block-local exclusive
    if (threadIdx.x == 255) blockSums[blockIdx.x] = lds[255];
}

__global__ __launch_bounds__(256) void scan_sums_kernel(int* __restrict__ blockSums, int nb) {
    __shared__ int lds[256];
    int v = (threadIdx.x < nb) ? blockSums[threadIdx.x] : 0;
    lds[threadIdx.x] = v;
    __syncthreads();
    for (int off = 1; off < 256; off <<= 1) {
        int t = (threadIdx.x >= off) ? lds[threadIdx.x - off] : 0;
        __syncthreads();
        lds[threadIdx.x] += t;
        __syncthreads();
    }
    if (threadIdx.x < nb) blockSums[threadIdx.x] = lds[threadIdx.x] - v;
    if (threadIdx.x == 255) blockSums[nb] = lds[255];  // total
}

__global__ void scan_finalize_kernel(int* __restrict__ row_ptr, int* __restrict__ cursor,
                                     const int* __restrict__ blockSums, int n, int nb) {
    int i = blockIdx.x * blockDim.x + threadIdx.x;
    if (i < n) {
        int v = row_ptr[i] + blockSums[i >> 8];
        row_ptr[i] = v;
        cursor[i] = v;  // write pointer for scatter
    } else if (i == n) {
        row_ptr[n] = blockSums[nb];
    }
}

__global__ __launch_bounds__(256) void scatter_kernel(
    const int* __restrict__ src, const int* __restrict__ dst,
    int* __restrict__ cursor, int* __restrict__ col, int e, int T) {
    int i0 = blockIdx.x * 256 + threadIdx.x;
    int s[4], d[4];
#pragma unroll
    for (int j = 0; j < 4; j++) {
        int ij = i0 + j * T;
        bool v = ij < e;
        s[j] = v ? src[ij] : 0;
        d[j] = v ? dst[ij] : -1;
    }
    int p[4];
#pragma unroll
    for (int j = 0; j < 4; j++) {
        p[j] = (d[j] >= 0) ? atomicAdd(&cursor[d[j]], 1) : 0;
    }
#pragma unroll
    for (int j = 0; j < 4; j++) {
        if (d[j] >= 0) col[p[j]] = s[j];
    }
}

// ---------------- W fragment pre-pack for MFMA B-operand -------------------
// Wf[((t*4+s)*64+lane)*8 + j] = bf16( W[(s*32 + (lane>>4)*8 + j)*OUT + t*16 + (lane&15)] )

template <int OUT>
__global__ __launch_bounds__(256) void pack_w_kernel(
    const float* __restrict__ W, unsigned short* __restrict__ Wf) {
    constexpr int T = OUT / 16, S = 4;
    int idx = blockIdx.x * 256 + threadIdx.x;
    if (idx >= T * S * 64) return;
    int lane = idx & 63;
    int ts = idx >> 6;
    int s = ts & (S - 1);
    int t = ts / S;
    int quad = lane >> 4, cn = lane & 15;
#pragma unroll
    for (int j = 0; j < 8; j++) {
        Wf[idx * 8 + j] = f2bf(W[(s * 32 + quad * 8 + j) * OUT + t * 16 + cn]);
    }
}

// ---------------- layer-0 transform (K=8, VALU): h(bf16)=x@W, as/ad --------

template <int K, int OUT, int HEADS>
__global__ __launch_bounds__(OUT) void transform_kernel(
    const float* __restrict__ x, const float* __restrict__ W,
    const float* __restrict__ a_src, const float* __restrict__ a_dst,
    unsigned short* __restrict__ h, float* __restrict__ as_o, float* __restrict__ ad_o,
    int n) {
    constexpr int NPB = 8;
    __shared__ float xs[NPB][K];
    const int tid = threadIdx.x;
    const int node0 = blockIdx.x * NPB;

    for (int idx = tid; idx < NPB * K; idx += OUT) {
        int ni = idx / K, k = idx - ni * K;
        int ng = node0 + ni;
        xs[ni][k] = (ng < n) ? x[(size_t)ng * K + k] : 0.f;
    }
    __syncthreads();

    float acc[NPB];
#pragma unroll
    for (int i = 0; i < NPB; i++) acc[i] = 0.f;
    for (int k = 0; k < K; k++) {
        float wk = W[k * OUT + tid];
#pragma unroll
        for (int i = 0; i < NPB; i++) acc[i] += xs[i][k] * wk;
    }

    const int lane = tid & 63;
    const int head = (HEADS == 2) ? (tid >> 6) : 0;
    const float av = a_src[tid];
    const float dv = a_dst[tid];
#pragma unroll
    for (int i = 0; i < NPB; i++) {
        int ng = node0 + i;
        if (ng >= n) break;
        h[(size_t)ng * OUT + tid] = f2bf(acc[i]);
        float ps = acc[i] * av, pd = acc[i] * dv;
        for (int off = 32; off; off >>= 1) {
            ps += __shfl_xor(ps, off, 64);
            pd += __shfl_xor(pd, off, 64);
        }
        if (lane == 0) {
            as_o[ng * HEADS + head] = ps;
            ad_o[ng * HEADS + head] = pd;
        }
    }
}

// ---------------- MFMA transform (K=128): h(bf16)=xb(bf16)@W, as/ad --------
// One wave per 16 nodes. A frag: A[m=lane&15][k=quad*8+j]; B from Wf packed;
// C: col=lane&15 (channel), row=quad*4+reg (node).

template <int OUT, int HEADS>
__global__ __launch_bounds__(256) void transform_mfma_kernel(
    const unsigned short* __restrict__ xb, const unsigned short* __restrict__ Wf,
    const float* __restrict__ a_src, const float* __restrict__ a_dst,
    unsigned short* __restrict__ h, float* __restrict__ as_o, float* __restrict__ ad_o,
    int n) {
    constexpr int T = OUT / 16, S = 4;  // K = 128
    const int w = threadIdx.x >> 6, lane = threadIdx.x & 63;
    const int node0 = (blockIdx.x * 4 + w) * 16;
    if (node0 >= n) return;
    const int quad = lane >> 4, col = lane & 15;

    const int arow = node0 + col;
    const bool aok = arow < n;
    bf16x8 a[S];
    const unsigned short* xrow = xb + (size_t)arow * 128 + quad * 8;
#pragma unroll
    for (int s = 0; s < S; s++) {
        bf16x8 z = {0, 0, 0, 0, 0, 0, 0, 0};
        a[s] = aok ? *(const bf16x8*)(xrow + s * 32) : z;
    }

    f32x4 acc[T];
#pragma unroll
    for (int t = 0; t < T; t++) acc[t] = (f32x4){0.f, 0.f, 0.f, 0.f};

#pragma unroll
    for (int s = 0; s < S; s++) {
#pragma unroll
        for (int t = 0; t < T; t++) {
            bf16x8 b = *(const bf16x8*)(Wf + ((size_t)(t * S + s) * 64 + lane) * 8);
            acc[t] = __builtin_amdgcn_mfma_f32_16x16x32_bf16(a[s], b, acc[t], 0, 0, 0);
        }
    }

    // store h (bf16)
#pragma unroll
    for (int t = 0; t < T; t++) {
#pragma unroll
        for (int r = 0; r < 4; r++) {
            int m = node0 + quad * 4 + r;
            if (m < n) h[(size_t)m * OUT + t * 16 + col] = f2bf(acc[t][r]);
        }
    }

    // as/ad epilogue: per node row, dot over channels then 16-lane reduce
#pragma unroll
    for (int r = 0; r < 4; r++) {
        float s0 = 0.f, s1 = 0.f, d0 = 0.f, d1 = 0.f;
#pragma unroll
        for (int t = 0; t < T; t++) {
            float av = a_src[t * 16 + col];
            float dv = a_dst[t * 16 + col];
            float v = acc[t][r];
            if (HEADS == 2 && t >= T / 2) { s1 += v * av; d1 += v * dv; }
            else                          { s0 += v * av; d0 += v * dv; }
        }
        for (int off = 8; off; off >>= 1) {
            s0 += __shfl_xor(s0, off, 64);
            d0 += __shfl_xor(d0, off, 64);
            if (HEADS == 2) {
                s1 += __shfl_xor(s1, off, 64);
                d1 += __shfl_xor(d1, off, 64);
            }
        }
        int m = node0 + quad * 4 + r;
        if (m < n) {
            if (HEADS == 2) {
                if (col == 0)      { as_o[m * 2] = s0;     ad_o[m * 2] = d0; }
                else if (col == 1) { as_o[m * 2 + 1] = s1; ad_o[m * 2 + 1] = d1; }
            } else {
                if (col == 0) { as_o[m] = s0; ad_o[m] = d0; }
            }
        }
    }
}

// ---------------- GAT aggregation, 2 heads: one wave per node --------------
// Output packed bf16 (uint = 2 channels) feeding the next MFMA transform.

template <int ACT>  // 1 = elu
__global__ __launch_bounds__(256) void agg2_kernel(
    const int* __restrict__ row_ptr, const int* __restrict__ col,
    const unsigned int* __restrict__ h2, const float2* __restrict__ as2,
    const float2* __restrict__ ad2, const float* __restrict__ bias,
    unsigned int* __restrict__ out, int n) {
    const int node = blockIdx.x * 4 + (threadIdx.x >> 6);
    const int lane = threadIdx.x & 63;
    if (node >= n) return;
    const bool hih = lane >= 32;

    const int beg = row_ptr[node], end = row_ptr[node + 1];
    const float2 adv = ad2[node];

    // self-loop contribution
    const float2 avs = as2[node];
    float w0s = __expf(LRELU(avs.x + adv.x));
    float w1s = __expf(LRELU(avs.y + adv.y));
    unsigned int us = h2[(size_t)node * 64 + lane];
    float wS = hih ? w1s : w0s;
    float accL = wS * bf_lo(us), accH = wS * bf_hi(us);
    float den0 = w0s, den1 = w1s;

    for (int base = beg; base < end; base += 64) {
        int cnt = end - base;
        if (cnt > 64) cnt = 64;
        int s = 0;
        float w0 = 0.f, w1 = 0.f;
        if (lane < cnt) {
            s = col[base + lane];
            float2 av = as2[s];
            w0 = __expf(LRELU(av.x + adv.x));
            w1 = __expf(LRELU(av.y + adv.y));
        }
        float t0 = w0, t1 = w1;
        for (int off = 32; off; off >>= 1) {
            t0 += __shfl_xor(t0, off, 64);
            t1 += __shfl_xor(t1, off, 64);
        }
        den0 += t0;
        den1 += t1;

        int j = 0;
        for (; j + 3 < cnt; j += 4) {
            int sA = __builtin_amdgcn_readlane(s, j);
            int sB = __builtin_amdgcn_readlane(s, j + 1);
            int sC = __builtin_amdgcn_readlane(s, j + 2);
            int sD = __builtin_amdgcn_readlane(s, j + 3);
            float a0 = readlane_f(w0, j),      a1 = readlane_f(w1, j);
            float b0_ = readlane_f(w0, j + 1), b1_ = readlane_f(w1, j + 1);
            float c0 = readlane_f(w0, j + 2),  c1 = readlane_f(w1, j + 2);
            float d0 = readlane_f(w0, j + 3),  d1 = readlane_f(w1, j + 3);
            unsigned int uA = h2[(size_t)sA * 64 + lane];
            unsigned int uB = h2[(size_t)sB * 64 + lane];
            unsigned int uC = h2[(size_t)sC * 64 + lane];
            unsigned int uD = h2[(size_t)sD * 64 + lane];
            float wA = hih ? a1 : a0;
            float wB = hih ? b1_ : b0_;
            float wC = hih ? c1 : c0;
            float wD = hih ? d1 : d0;
            accL += wA * bf_lo(uA); accH += wA * bf_hi(uA);
            accL += wB * bf_lo(uB); accH += wB * bf_hi(uB);
            accL += wC * bf_lo(uC); accH += wC * bf_hi(uC);
            accL += wD * bf_lo(uD); accH += wD * bf_hi(uD);
        }
        for (; j < cnt; j++) {
            int sA = __builtin_amdgcn_readlane(s, j);
            float a0 = readlane_f(w0, j), a1 = readlane_f(w1, j);
            float wA = hih ? a1 : a0;
            unsigned int uA = h2[(size_t)sA * 64 + lane];
            accL += wA * bf_lo(uA);
            accH += wA * bf_hi(uA);
        }
    }

    float den = hih ? den1 : den0;
    float inv = 1.f / (den + 1e-16f);
    float2 bv = ((const float2*)bias)[lane];
    float oL = accL * inv + bv.x;
    float oH = accH * inv + bv.y;
    if (ACT) {
        oL = oL > 0.f ? oL : expm1f(oL);
        oH = oH > 0.f ? oH : expm1f(oH);
    }
    out[(size_t)node * 64 + lane] =
        ((unsigned int)f2bf(oH) << 16) | (unsigned int)f2bf(oL);
}

// ---------------- GAT aggregation, 1 head (layer 2) ------------------------

__global__ __launch_bounds__(256) void agg1_kernel(
    const int* __restrict__ row_ptr, const int* __restrict__ col,
    const unsigned int* __restrict__ h2, const float* __restrict__ as1,
    const float* __restrict__ ad1, const float* __restrict__ bias,
    float* __restrict__ out, int n) {
    const int node = blockIdx.x * 4 + (threadIdx.x >> 6);
    const int lane = threadIdx.x & 63;
    if (node >= n) return;
    const int m = lane & 31;
    const bool hih = lane >= 32;

    const int beg = row_ptr[node], end = row_ptr[node + 1];
    const float adv = ad1[node];

    float ws = __expf(LRELU(as1[node] + adv));
    float den = ws;
    float accL = 0.f, accH = 0.f;
    {
        unsigned int u = h2[(size_t)node * 32 + m];
        if (!hih) {
            accL = ws * bf_lo(u);
            accH = ws * bf_hi(u);
        }
    }

    for (int base = beg; base < end; base += 64) {
        int cnt = end - base;
        if (cnt > 64) cnt = 64;
        int s = 0;
        float w = 0.f;
        if (lane < cnt) {
            s = col[base + lane];
            w = __expf(LRELU(as1[s] + adv));
        }
        float t = w;
        for (int off = 32; off; off >>= 1) t += __shfl_xor(t, off, 64);
        den += t;

        int j = 0;
        for (; j + 3 < cnt; j += 4) {
            int sA = __builtin_amdgcn_readlane(s, j);
            int sB = __builtin_amdgcn_readlane(s, j + 1);
            int sC = __builtin_amdgcn_readlane(s, j + 2);
            int sD = __builtin_amdgcn_readlane(s, j + 3);
            float wA = readlane_f(w, j),     wB = readlane_f(w, j + 1);
            float wC = readlane_f(w, j + 2), wD = readlane_f(w, j + 3);
            int s1_ = hih ? sB : sA;
            int s2_ = hih ? sD : sC;
            float w1_ = hih ? wB : wA;
            float w2_ = hih ? wD : wC;
            unsigned int u1 = h2[(size_t)s1_ * 32 + m];
            unsigned int u2 = h2[(size_t)s2_ * 32 + m];
            accL += w1_ * bf_lo(u1); accH += w1_ * bf_hi(u1);
            accL += w2_ * bf_lo(u2); accH += w2_ * bf_hi(u2);
        }
        for (; j < cnt; j += 2) {
            int sA = __builtin_amdgcn_readlane(s, j);
            float wA = readlane_f(w, j);
            int jb = j + 1 < 64 ? j + 1 : 63;
            int sB = __builtin_amdgcn_readlane(s, jb);
            float wB = (j + 1 < cnt) ? readlane_f(w, jb) : 0.f;
            int s1_ = hih ? sB : sA;
            float w1_ = hih ? wB : wA;
            unsigned int u1 = h2[(size_t)s1_ * 32 + m];
            accL += w1_ * bf_lo(u1);
            accH += w1_ * bf_hi(u1);
        }
    }

    accL += __shfl_xor(accL, 32, 64);
    accH += __shfl_xor(accH, 32, 64);
    if (!hih) {
        float inv = 1.f / (den + 1e-16f);
        float2 bv = ((const float2*)bias)[m];
        float oL = accL * inv + bv.x;
        float oH = accH * inv + bv.y;
        ((float2*)out)[(size_t)node * 32 + m] = make_float2(oL, oH);
    }
}

// ---------------- mean pool over sorted batch ------------------------------

__global__ __launch_bounds__(256) void pool_kernel(
    const float* __restrict__ x, const int* __restrict__ batch,
    float* __restrict__ pooled, float* __restrict__ cnt, int n) {
    const int NPW = 16;
    int wid = blockIdx.x * (blockDim.x >> 6) + (threadIdx.x >> 6);
    int lane = threadIdx.x & 63;
    int start = wid * NPW;
    if (start >= n) return;
    int end = min(start + NPW, n);
    float acc = 0.f, c = 0.f;
    int cur = -1;
    for (int i = start; i < end; i++) {
        int b = batch[i];
        if (b != cur) {
            if (cur >= 0) {
                atomicAdd(&pooled[cur * 64 + lane], acc);
                if (lane == 0) atomicAdd(&cnt[cur], c);
            }
            cur = b;
            acc = 0.f;
            c = 0.f;
        }
        acc += x[(size_t)i * 64 + lane];
        c += 1.f;
    }
    if (cur >= 0) {
        atomicAdd(&pooled[cur * 64 + lane], acc);
        if (lane == 0) atomicAdd(&cnt[cur], c);
    }
}

// ---------------- MLP head: one block per graph row ------------------------

__global__ __launch_bounds__(256) void mlp_kernel(
    const float* __restrict__ pooled, const float* __restrict__ cnt,
    const float* __restrict__ obs,
    const float* __restrict__ Ws1, const float* __restrict__ bs1,
    const float* __restrict__ ln_g, const float* __restrict__ ln_b,
    const float* __restrict__ Ws2, const float* __restrict__ bs2,
    const float* __restrict__ Wa, const float* __restrict__ ba,
    const float* __restrict__ Wc, const float* __restrict__ bc,
    float* __restrict__ out_logits, float* __restrict__ out_value) {
    int b = blockIdx.x;
    int t = threadIdx.x;
    __shared__ float comb[192];
    __shared__ float red[256];
    __shared__ float hs[256];

    if (t < 64) {
        float c = cnt[b];
        c = c > 1.f ? c : 1.f;
        comb[t] = pooled[b * 64 + t] / c;
    } else if (t < 192) {
        comb[t] = obs[b * 128 + (t - 64)];
    }
    __syncthreads();

    float acc = bs1[t];
    for (int k = 0; k < 192; k++) acc += comb[k] * Ws1[k * 256 + t];

    red[t] = acc;
    __syncthreads();
    for (int off = 128; off; off >>= 1) {
        if (t < off) red[t] += red[t + off];
        __syncthreads();
    }
    float mu = red[0] / 256.f;
    __syncthreads();
    float d = acc - mu;
    red[t] = d * d;
    __syncthreads();
    for (int off = 128; off; off >>= 1) {
        if (t < off) red[t] += red[t + off];
        __syncthreads();
    }
    float var = red[0] / 256.f;
    float hn = d * rsqrtf(var + 1e-5f) * ln_g[t] + ln_b[t];
    hn = hn > 0.f ? hn : 0.f;
    __syncthreads();
    hs[t] = hn;
    __syncthreads();

    float acc2 = bs2[t];
    for (int k = 0; k < 256; k++) acc2 += hs[k] * Ws2[k * 256 + t];
    acc2 = acc2 > 0.f ? acc2 : 0.f;
    __syncthreads();
    hs[t] = acc2;
    __syncthreads();

    if (t < 16) {
        float a = ba[t];
        for (int k = 0; k < 256; k++) a += hs[k] * Wa[k * 16 + t];
        out_logits[b * 16 + t] = a;
    } else if (t == 16) {
        float v = bc[0];
        for (int k = 0; k < 256; k++) v += hs[k] * Wc[k];
        out_value[b] = v;
    }
}

// ---------------------------------------------------------------------------

extern "C" void kernel_launch(void* const* d_in, const int* in_sizes, int n_in,
                              void* d_out, int out_size, void* d_ws, size_t ws_size,
                              hipStream_t stream) {
    const float* obs    = (const float*)d_in[0];
    const float* nf     = (const float*)d_in[1];
    const int*   ei     = (const int*)d_in[2];
    const int*   batch  = (const int*)d_in[3];
    const float* W0     = (const float*)d_in[4];
    const float* a_src0 = (const float*)d_in[5];
    const float* a_dst0 = (const float*)d_in[6];
    const float* b0     = (const float*)d_in[7];
    const float* W1     = (const float*)d_in[8];
    const float* a_src1 = (const float*)d_in[9];
    const float* a_dst1 = (const float*)d_in[10];
    const float* b1     = (const float*)d_in[11];
    const float* W2     = (const float*)d_in[12];
    const float* a_src2 = (const float*)d_in[13];
    const float* a_dst2 = (const float*)d_in[14];
    const float* b2     = (const float*)d_in[15];
    const float* Ws1    = (const float*)d_in[16];
    const float* bs1    = (const float*)d_in[17];
    const float* ln_g   = (const float*)d_in[18];
    const float* ln_b   = (const float*)d_in[19];
    const float* Ws2    = (const float*)d_in[20];
    const float* bs2    = (const float*)d_in[21];
    const float* Wa     = (const float*)d_in[22];
    const float* ba     = (const float*)d_in[23];
    const float* Wc     = (const float*)d_in[24];
    const float* bc     = (const float*)d_in[25];

    const int N = in_sizes[3];
    const int E = in_sizes[2] / 2;
    const int B = in_sizes[0] / 128;
    const int* src = ei;
    const int* dstp = ei + E;

    // workspace carve (256B aligned)
    char* p = (char*)d_ws;
    auto alloc = [&](size_t bytes) -> void* {
        void* r = (void*)p;
        p += (bytes + 255) & ~(size_t)255;
        return r;
    };
    int nb = (N + 255) / 256;
    int*   cursor    = (int*)alloc((size_t)N * 4);
    int*   row_ptr   = (int*)alloc((size_t)(N + 1) * 4);
    int*   blockSums = (int*)alloc((size_t)(nb + 1) * 4);
    int*   col       = (int*)alloc((size_t)E * 4);
    unsigned short* hbuf = (unsigned short*)alloc((size_t)N * 128 * 2);  // bf16
    unsigned int*   xb   = (unsigned int*)alloc((size_t)N * 64 * 4);    // bf16x2 features
    float* xbuf      = (float*)alloc((size_t)N * 64 * 4);               // final layer fp32
    float* as_       = (float*)alloc((size_t)N * 2 * 4);
    float* ad_       = (float*)alloc((size_t)N * 2 * 4);
    unsigned short* Wf1 = (unsigned short*)alloc((size_t)8 * 4 * 64 * 8 * 2);
    unsigned short* Wf2 = (unsigned short*)alloc((size_t)4 * 4 * 64 * 8 * 2);
    float* pooled    = (float*)alloc((size_t)(B * 64 + B) * 4);
    float* cnt       = pooled + (size_t)B * 64;

    float* out_logits = (float*)d_out;
    float* out_value  = out_logits + (size_t)B * 16;

    // ---- CSR build (by dst, real edges only; self-loops implicit in agg) ----
    hipMemsetAsync(cursor, 0, (size_t)N * 4, stream);
    {
        int blocks = (E + 8 * 256 - 1) / (8 * 256);
        int T = blocks * 256;
        count_kernel<<<blocks, 256, 0, stream>>>(dstp, cursor, E, T);
    }
    scan_block_kernel<<<nb, 256, 0, stream>>>(cursor, row_ptr, blockSums, N);
    scan_sums_kernel<<<1, 256, 0, stream>>>(blockSums, nb);
    scan_finalize_kernel<<<(N + 1 + 255) / 256, 256, 0, stream>>>(row_ptr, cursor, blockSums, N, nb);
    {
        int blocks = (E + 4 * 256 - 1) / (4 * 256);
        int T = blocks * 256;
        scatter_kernel<<<blocks, 256, 0, stream>>>(src, dstp, cursor, col, E, T);
    }

    // ---- pack W fragments + zero pooled/cnt ----
    pack_w_kernel<128><<<8, 256, 0, stream>>>(W1, Wf1);
    pack_w_kernel<64><<<4, 256, 0, stream>>>(W2, Wf2);
    hipMemsetAsync(pooled, 0, (size_t)(B * 64 + B) * 4, stream);

    // ---- GAT layer 0: in=8 -> h=[N,2,64] concat, elu ----
    transform_kernel<8, 128, 2><<<(N + 7) / 8, 128, 0, stream>>>(
        nf, W0, a_src0, a_dst0, hbuf, as_, ad_, N);
    agg2_kernel<1><<<(N + 3) / 4, 256, 0, stream>>>(
        row_ptr, col, (const unsigned int*)hbuf, (const float2*)as_,
        (const float2*)ad_, b0, xb, N);

    // ---- GAT layer 1: in=128 -> concat, elu (MFMA transform) ----
    transform_mfma_kernel<128, 2><<<(N + 63) / 64, 256, 0, stream>>>(
        (const unsigned short*)xb, Wf1, a_src1, a_dst1, hbuf, as_, ad_, N);
    agg2_kernel<1><<<(N + 3) / 4, 256, 0, stream>>>(
        row_ptr, col, (const unsigned int*)hbuf, (const float2*)as_,
        (const float2*)ad_, b1, xb, N);

    // ---- GAT layer 2: in=128 -> heads=1, out=64 (MFMA transform) ----
    transform_mfma_kernel<64, 1><<<(N + 63) / 64, 256, 0, stream>>>(
        (const unsigned short*)xb, Wf2, a_src2, a_dst2, hbuf, as_, ad_, N);
    agg1_kernel<<<(N + 3) / 4, 256, 0, stream>>>(
        row_ptr, col, (const unsigned int*)hbuf, as_, ad_, b2, xbuf, N);

    // ---- mean pool + MLP head ----
    {
        int waves = (N + 15) / 16;
        int blocks = (waves + 3) / 4;
        pool_kernel<<<blocks, 256, 0, stream>>>(xbuf, batch, pooled, cnt, N);
    }
    mlp_kernel<<<B, 256, 0, stream>>>(pooled, cnt, obs, Ws1, bs1, ln_g, ln_b,
                                      Ws2, bs2, Wa, ba, Wc, bc,
                                      out_logits, out_value);
}

// Round 8
// 398.419 us; speedup vs baseline: 1.6231x; 1.0183x over previous
//
#include <hip/hip_runtime.h>
#include <math.h>

// ---------------------------------------------------------------------------
// GATPolicy: 3x GATConv (with self loops) + mean-pool + MLP head.
// CSR-by-dst (real edges only; self-loops implicit in agg). Cursor counters
// replicated 8x (copy = blockIdx&7, XCD-local under round-robin dispatch) so
// atomic RMW lines stay in one L2. count/scatter use IDENTICAL grid + ILP-8
// stride so the edge->copy mapping matches exactly. cursor8/total alias the
// xbuf region (CSR build finishes before xbuf is first written).
// Inter-layer features bf16; K=128 transforms via mfma_f32_16x16x32_bf16.
// ---------------------------------------------------------------------------

#define LRELU(x) ((x) > 0.f ? (x) : 0.2f * (x))

typedef short bf16x8 __attribute__((ext_vector_type(8)));
typedef float f32x4 __attribute__((ext_vector_type(4)));

__device__ __forceinline__ float readlane_f(float v, int lane) {
    return __int_as_float(__builtin_amdgcn_readlane(__float_as_int(v), lane));
}
__device__ __forceinline__ unsigned short f2bf(float f) {
    unsigned int u = __float_as_uint(f);
    u = (u + 0x7fffu + ((u >> 16) & 1u)) >> 16;  // RNE
    return (unsigned short)u;
}
__device__ __forceinline__ float bf_lo(unsigned int u) { return __uint_as_float(u << 16); }
__device__ __forceinline__ float bf_hi(unsigned int u) { return __uint_as_float(u & 0xffff0000u); }

// ---------------- CSR build (XCD-local cursors, ILP-batched) ----------------

__global__ __launch_bounds__(256) void count_kernel(
    const int* __restrict__ dst, int* __restrict__ cursor8, int e, int T, int n) {
    int i0 = blockIdx.x * 256 + threadIdx.x;
    int* my = cursor8 + (size_t)(blockIdx.x & 7) * n;
    int d[8];
#pragma unroll
    for (int j = 0; j < 8; j++) {
        int ij = i0 + j * T;
        d[j] = (ij < e) ? dst[ij] : -1;
    }
#pragma unroll
    for (int j = 0; j < 8; j++) {
        if (d[j] >= 0) atomicAdd(&my[d[j]], 1);
    }
}

// total[i] = sum over 8 copies
__global__ __launch_bounds__(256) void sum8_kernel(
    const int* __restrict__ cursor8, int* __restrict__ total, int n) {
    int i = blockIdx.x * 256 + threadIdx.x;
    if (i >= n) return;
    int s = 0;
#pragma unroll
    for (int x = 0; x < 8; x++) s += cursor8[(size_t)x * n + i];
    total[i] = s;
}

__global__ __launch_bounds__(256) void scan_block_kernel(
    const int* __restrict__ in, int* __restrict__ out_local,
    int* __restrict__ blockSums, int n) {
    __shared__ int lds[256];
    int i = blockIdx.x * 256 + threadIdx.x;
    int v = (i < n) ? in[i] : 0;
    lds[threadIdx.x] = v;
    __syncthreads();
    for (int off = 1; off < 256; off <<= 1) {
        int t = (threadIdx.x >= off) ? lds[threadIdx.x - off] : 0;
        __syncthreads();
        lds[threadIdx.x] += t;
        __syncthreads();
    }
    if (i < n) out_local[i] = lds[threadIdx.x] - v;  // block-local exclusive
    if (threadIdx.x == 255) blockSums[blockIdx.x] = lds[255];
}

__global__ __launch_bounds__(256) void scan_sums_kernel(int* __restrict__ blockSums, int nb) {
    __shared__ int lds[256];
    int v = (threadIdx.x < nb) ? blockSums[threadIdx.x] : 0;
    lds[threadIdx.x] = v;
    __syncthreads();
    for (int off = 1; off < 256; off <<= 1) {
        int t = (threadIdx.x >= off) ? lds[threadIdx.x - off] : 0;
        __syncthreads();
        lds[threadIdx.x] += t;
        __syncthreads();
    }
    if (threadIdx.x < nb) blockSums[threadIdx.x] = lds[threadIdx.x] - v;
    if (threadIdx.x == 255) blockSums[nb] = lds[255];  // total
}

// row_ptr[i] = global exclusive prefix; cursor8 copies become the 8 per-copy
// write pointers (sub-segments of the row, prefix over copies).
__global__ void scan_finalize_kernel(int* __restrict__ row_ptr, int* __restrict__ cursor8,
                                     const int* __restrict__ blockSums, int n, int nb) {
    int i = blockIdx.x * blockDim.x + threadIdx.x;
    if (i < n) {
        int base = row_ptr[i] + blockSums[i >> 8];
        row_ptr[i] = base;
        int run = base;
#pragma unroll
        for (int x = 0; x < 8; x++) {
            int c = cursor8[(size_t)x * n + i];
            cursor8[(size_t)x * n + i] = run;
            run += c;
        }
    } else if (i == n) {
        row_ptr[n] = blockSums[nb];
    }
}

// IDENTICAL grid + ILP-8 stride as count_kernel -> same edge->copy mapping.
__global__ __launch_bounds__(256) void scatter_kernel(
    const int* __restrict__ src, const int* __restrict__ dst,
    int* __restrict__ cursor8, int* __restrict__ col, int e, int T, int n) {
    int i0 = blockIdx.x * 256 + threadIdx.x;
    int* my = cursor8 + (size_t)(blockIdx.x & 7) * n;
    int s[8], d[8];
#pragma unroll
    for (int j = 0; j < 8; j++) {
        int ij = i0 + j * T;
        bool v = ij < e;
        s[j] = v ? src[ij] : 0;
        d[j] = v ? dst[ij] : -1;
    }
    int p[8];
#pragma unroll
    for (int j = 0; j < 8; j++) {
        p[j] = (d[j] >= 0) ? atomicAdd(&my[d[j]], 1) : 0;
    }
#pragma unroll
    for (int j = 0; j < 8; j++) {
        if (d[j] >= 0) col[p[j]] = s[j];
    }
}

// ---------------- W fragment pre-pack for MFMA B-operand -------------------

template <int OUT>
__global__ __launch_bounds__(256) void pack_w_kernel(
    const float* __restrict__ W, unsigned short* __restrict__ Wf) {
    constexpr int T = OUT / 16, S = 4;
    int idx = blockIdx.x * 256 + threadIdx.x;
    if (idx >= T * S * 64) return;
    int lane = idx & 63;
    int ts = idx >> 6;
    int s = ts & (S - 1);
    int t = ts / S;
    int quad = lane >> 4, cn = lane & 15;
#pragma unroll
    for (int j = 0; j < 8; j++) {
        Wf[idx * 8 + j] = f2bf(W[(s * 32 + quad * 8 + j) * OUT + t * 16 + cn]);
    }
}

// ---------------- layer-0 transform (K=8, VALU): h(bf16)=x@W, as/ad --------

template <int K, int OUT, int HEADS>
__global__ __launch_bounds__(OUT) void transform_kernel(
    const float* __restrict__ x, const float* __restrict__ W,
    const float* __restrict__ a_src, const float* __restrict__ a_dst,
    unsigned short* __restrict__ h, float* __restrict__ as_o, float* __restrict__ ad_o,
    int n) {
    constexpr int NPB = 8;
    __shared__ float xs[NPB][K];
    const int tid = threadIdx.x;
    const int node0 = blockIdx.x * NPB;

    for (int idx = tid; idx < NPB * K; idx += OUT) {
        int ni = idx / K, k = idx - ni * K;
        int ng = node0 + ni;
        xs[ni][k] = (ng < n) ? x[(size_t)ng * K + k] : 0.f;
    }
    __syncthreads();

    float acc[NPB];
#pragma unroll
    for (int i = 0; i < NPB; i++) acc[i] = 0.f;
    for (int k = 0; k < K; k++) {
        float wk = W[k * OUT + tid];
#pragma unroll
        for (int i = 0; i < NPB; i++) acc[i] += xs[i][k] * wk;
    }

    const int lane = tid & 63;
    const int head = (HEADS == 2) ? (tid >> 6) : 0;
    const float av = a_src[tid];
    const float dv = a_dst[tid];
#pragma unroll
    for (int i = 0; i < NPB; i++) {
        int ng = node0 + i;
        if (ng >= n) break;
        h[(size_t)ng * OUT + tid] = f2bf(acc[i]);
        float ps = acc[i] * av, pd = acc[i] * dv;
        for (int off = 32; off; off >>= 1) {
            ps += __shfl_xor(ps, off, 64);
            pd += __shfl_xor(pd, off, 64);
        }
        if (lane == 0) {
            as_o[ng * HEADS + head] = ps;
            ad_o[ng * HEADS + head] = pd;
        }
    }
}

// ---------------- MFMA transform (K=128): h(bf16)=xb(bf16)@W, as/ad --------

template <int OUT, int HEADS>
__global__ __launch_bounds__(256) void transform_mfma_kernel(
    const unsigned short* __restrict__ xb, const unsigned short* __restrict__ Wf,
    const float* __restrict__ a_src, const float* __restrict__ a_dst,
    unsigned short* __restrict__ h, float* __restrict__ as_o, float* __restrict__ ad_o,
    int n) {
    constexpr int T = OUT / 16, S = 4;  // K = 128
    const int w = threadIdx.x >> 6, lane = threadIdx.x & 63;
    const int node0 = (blockIdx.x * 4 + w) * 16;
    if (node0 >= n) return;
    const int quad = lane >> 4, col = lane & 15;

    const int arow = node0 + col;
    const bool aok = arow < n;
    bf16x8 a[S];
    const unsigned short* xrow = xb + (size_t)arow * 128 + quad * 8;
#pragma unroll
    for (int s = 0; s < S; s++) {
        bf16x8 z = {0, 0, 0, 0, 0, 0, 0, 0};
        a[s] = aok ? *(const bf16x8*)(xrow + s * 32) : z;
    }

    f32x4 acc[T];
#pragma unroll
    for (int t = 0; t < T; t++) acc[t] = (f32x4){0.f, 0.f, 0.f, 0.f};

#pragma unroll
    for (int s = 0; s < S; s++) {
#pragma unroll
        for (int t = 0; t < T; t++) {
            bf16x8 b = *(const bf16x8*)(Wf + ((size_t)(t * S + s) * 64 + lane) * 8);
            acc[t] = __builtin_amdgcn_mfma_f32_16x16x32_bf16(a[s], b, acc[t], 0, 0, 0);
        }
    }

#pragma unroll
    for (int t = 0; t < T; t++) {
#pragma unroll
        for (int r = 0; r < 4; r++) {
            int m = node0 + quad * 4 + r;
            if (m < n) h[(size_t)m * OUT + t * 16 + col] = f2bf(acc[t][r]);
        }
    }

#pragma unroll
    for (int r = 0; r < 4; r++) {
        float s0 = 0.f, s1 = 0.f, d0 = 0.f, d1 = 0.f;
#pragma unroll
        for (int t = 0; t < T; t++) {
            float av = a_src[t * 16 + col];
            float dv = a_dst[t * 16 + col];
            float v = acc[t][r];
            if (HEADS == 2 && t >= T / 2) { s1 += v * av; d1 += v * dv; }
            else                          { s0 += v * av; d0 += v * dv; }
        }
        for (int off = 8; off; off >>= 1) {
            s0 += __shfl_xor(s0, off, 64);
            d0 += __shfl_xor(d0, off, 64);
            if (HEADS == 2) {
                s1 += __shfl_xor(s1, off, 64);
                d1 += __shfl_xor(d1, off, 64);
            }
        }
        int m = node0 + quad * 4 + r;
        if (m < n) {
            if (HEADS == 2) {
                if (col == 0)      { as_o[m * 2] = s0;     ad_o[m * 2] = d0; }
                else if (col == 1) { as_o[m * 2 + 1] = s1; ad_o[m * 2 + 1] = d1; }
            } else {
                if (col == 0) { as_o[m] = s0; ad_o[m] = d0; }
            }
        }
    }
}

// ---------------- GAT aggregation, 2 heads: one wave per node --------------

template <int ACT>  // 1 = elu
__global__ __launch_bounds__(256) void agg2_kernel(
    const int* __restrict__ row_ptr, const int* __restrict__ col,
    const unsigned int* __restrict__ h2, const float2* __restrict__ as2,
    const float2* __restrict__ ad2, const float* __restrict__ bias,
    unsigned int* __restrict__ out, int n) {
    const int node = blockIdx.x * 4 + (threadIdx.x >> 6);
    const int lane = threadIdx.x & 63;
    if (node >= n) return;
    const bool hih = lane >= 32;

    const int beg = row_ptr[node], end = row_ptr[node + 1];
    const float2 adv = ad2[node];

    const float2 avs = as2[node];
    float w0s = __expf(LRELU(avs.x + adv.x));
    float w1s = __expf(LRELU(avs.y + adv.y));
    unsigned int us = h2[(size_t)node * 64 + lane];
    float wS = hih ? w1s : w0s;
    float accL = wS * bf_lo(us), accH = wS * bf_hi(us);
    float den0 = w0s, den1 = w1s;

    for (int base = beg; base < end; base += 64) {
        int cnt = end - base;
        if (cnt > 64) cnt = 64;
        int s = 0;
        float w0 = 0.f, w1 = 0.f;
        if (lane < cnt) {
            s = col[base + lane];
            float2 av = as2[s];
            w0 = __expf(LRELU(av.x + adv.x));
            w1 = __expf(LRELU(av.y + adv.y));
        }
        float t0 = w0, t1 = w1;
        for (int off = 32; off; off >>= 1) {
            t0 += __shfl_xor(t0, off, 64);
            t1 += __shfl_xor(t1, off, 64);
        }
        den0 += t0;
        den1 += t1;

        int j = 0;
        for (; j + 3 < cnt; j += 4) {
            int sA = __builtin_amdgcn_readlane(s, j);
            int sB = __builtin_amdgcn_readlane(s, j + 1);
            int sC = __builtin_amdgcn_readlane(s, j + 2);
            int sD = __builtin_amdgcn_readlane(s, j + 3);
            float a0 = readlane_f(w0, j),      a1 = readlane_f(w1, j);
            float b0_ = readlane_f(w0, j + 1), b1_ = readlane_f(w1, j + 1);
            float c0 = readlane_f(w0, j + 2),  c1 = readlane_f(w1, j + 2);
            float d0 = readlane_f(w0, j + 3),  d1 = readlane_f(w1, j + 3);
            unsigned int uA = h2[(size_t)sA * 64 + lane];
            unsigned int uB = h2[(size_t)sB * 64 + lane];
            unsigned int uC = h2[(size_t)sC * 64 + lane];
            unsigned int uD = h2[(size_t)sD * 64 + lane];
            float wA = hih ? a1 : a0;
            float wB = hih ? b1_ : b0_;
            float wC = hih ? c1 : c0;
            float wD = hih ? d1 : d0;
            accL += wA * bf_lo(uA); accH += wA * bf_hi(uA);
            accL += wB * bf_lo(uB); accH += wB * bf_hi(uB);
            accL += wC * bf_lo(uC); accH += wC * bf_hi(uC);
            accL += wD * bf_lo(uD); accH += wD * bf_hi(uD);
        }
        for (; j < cnt; j++) {
            int sA = __builtin_amdgcn_readlane(s, j);
            float a0 = readlane_f(w0, j), a1 = readlane_f(w1, j);
            float wA = hih ? a1 : a0;
            unsigned int uA = h2[(size_t)sA * 64 + lane];
            accL += wA * bf_lo(uA);
            accH += wA * bf_hi(uA);
        }
    }

    float den = hih ? den1 : den0;
    float inv = 1.f / (den + 1e-16f);
    float2 bv = ((const float2*)bias)[lane];
    float oL = accL * inv + bv.x;
    float oH = accH * inv + bv.y;
    if (ACT) {
        oL = oL > 0.f ? oL : expm1f(oL);
        oH = oH > 0.f ? oH : expm1f(oH);
    }
    out[(size_t)node * 64 + lane] =
        ((unsigned int)f2bf(oH) << 16) | (unsigned int)f2bf(oL);
}

// ---------------- GAT aggregation, 1 head (layer 2) ------------------------

__global__ __launch_bounds__(256) void agg1_kernel(
    const int* __restrict__ row_ptr, const int* __restrict__ col,
    const unsigned int* __restrict__ h2, const float* __restrict__ as1,
    const float* __restrict__ ad1, const float* __restrict__ bias,
    float* __restrict__ out, int n) {
    const int node = blockIdx.x * 4 + (threadIdx.x >> 6);
    const int lane = threadIdx.x & 63;
    if (node >= n) return;
    const int m = lane & 31;
    const bool hih = lane >= 32;

    const int beg = row_ptr[node], end = row_ptr[node + 1];
    const float adv = ad1[node];

    float ws = __expf(LRELU(as1[node] + adv));
    float den = ws;
    float accL = 0.f, accH = 0.f;
    {
        unsigned int u = h2[(size_t)node * 32 + m];
        if (!hih) {
            accL = ws * bf_lo(u);
            accH = ws * bf_hi(u);
        }
    }

    for (int base = beg; base < end; base += 64) {
        int cnt = end - base;
        if (cnt > 64) cnt = 64;
        int s = 0;
        float w = 0.f;
        if (lane < cnt) {
            s = col[base + lane];
            w = __expf(LRELU(as1[s] + adv));
        }
        float t = w;
        for (int off = 32; off; off >>= 1) t += __shfl_xor(t, off, 64);
        den += t;

        int j = 0;
        for (; j + 3 < cnt; j += 4) {
            int sA = __builtin_amdgcn_readlane(s, j);
            int sB = __builtin_amdgcn_readlane(s, j + 1);
            int sC = __builtin_amdgcn_readlane(s, j + 2);
            int sD = __builtin_amdgcn_readlane(s, j + 3);
            float wA = readlane_f(w, j),     wB = readlane_f(w, j + 1);
            float wC = readlane_f(w, j + 2), wD = readlane_f(w, j + 3);
            int s1_ = hih ? sB : sA;
            int s2_ = hih ? sD : sC;
            float w1_ = hih ? wB : wA;
            float w2_ = hih ? wD : wC;
            unsigned int u1 = h2[(size_t)s1_ * 32 + m];
            unsigned int u2 = h2[(size_t)s2_ * 32 + m];
            accL += w1_ * bf_lo(u1); accH += w1_ * bf_hi(u1);
            accL += w2_ * bf_lo(u2); accH += w2_ * bf_hi(u2);
        }
        for (; j < cnt; j += 2) {
            int sA = __builtin_amdgcn_readlane(s, j);
            float wA = readlane_f(w, j);
            int jb = j + 1 < 64 ? j + 1 : 63;
            int sB = __builtin_amdgcn_readlane(s, jb);
            float wB = (j + 1 < cnt) ? readlane_f(w, jb) : 0.f;
            int s1_ = hih ? sB : sA;
            float w1_ = hih ? wB : wA;
            unsigned int u1 = h2[(size_t)s1_ * 32 + m];
            accL += w1_ * bf_lo(u1);
            accH += w1_ * bf_hi(u1);
        }
    }

    accL += __shfl_xor(accL, 32, 64);
    accH += __shfl_xor(accH, 32, 64);
    if (!hih) {
        float inv = 1.f / (den + 1e-16f);
        float2 bv = ((const float2*)bias)[m];
        float oL = accL * inv + bv.x;
        float oH = accH * inv + bv.y;
        ((float2*)out)[(size_t)node * 32 + m] = make_float2(oL, oH);
    }
}

// ---------------- mean pool over sorted batch ------------------------------

__global__ __launch_bounds__(256) void pool_kernel(
    const float* __restrict__ x, const int* __restrict__ batch,
    float* __restrict__ pooled, float* __restrict__ cnt, int n) {
    const int NPW = 16;
    int wid = blockIdx.x * (blockDim.x >> 6) + (threadIdx.x >> 6);
    int lane = threadIdx.x & 63;
    int start = wid * NPW;
    if (start >= n) return;
    int end = min(start + NPW, n);
    float acc = 0.f, c = 0.f;
    int cur = -1;
    for (int i = start; i < end; i++) {
        int b = batch[i];
        if (b != cur) {
            if (cur >= 0) {
                atomicAdd(&pooled[cur * 64 + lane], acc);
                if (lane == 0) atomicAdd(&cnt[cur], c);
            }
            cur = b;
            acc = 0.f;
            c = 0.f;
        }
        acc += x[(size_t)i * 64 + lane];
        c += 1.f;
    }
    if (cur >= 0) {
        atomicAdd(&pooled[cur * 64 + lane], acc);
        if (lane == 0) atomicAdd(&cnt[cur], c);
    }
}

// ---------------- MLP head: one block per graph row ------------------------

__global__ __launch_bounds__(256) void mlp_kernel(
    const float* __restrict__ pooled, const float* __restrict__ cnt,
    const float* __restrict__ obs,
    const float* __restrict__ Ws1, const float* __restrict__ bs1,
    const float* __restrict__ ln_g, const float* __restrict__ ln_b,
    const float* __restrict__ Ws2, const float* __restrict__ bs2,
    const float* __restrict__ Wa, const float* __restrict__ ba,
    const float* __restrict__ Wc, const float* __restrict__ bc,
    float* __restrict__ out_logits, float* __restrict__ out_value) {
    int b = blockIdx.x;
    int t = threadIdx.x;
    __shared__ float comb[192];
    __shared__ float red[256];
    __shared__ float hs[256];

    if (t < 64) {
        float c = cnt[b];
        c = c > 1.f ? c : 1.f;
        comb[t] = pooled[b * 64 + t] / c;
    } else if (t < 192) {
        comb[t] = obs[b * 128 + (t - 64)];
    }
    __syncthreads();

    float acc = bs1[t];
    for (int k = 0; k < 192; k++) acc += comb[k] * Ws1[k * 256 + t];

    red[t] = acc;
    __syncthreads();
    for (int off = 128; off; off >>= 1) {
        if (t < off) red[t] += red[t + off];
        __syncthreads();
    }
    float mu = red[0] / 256.f;
    __syncthreads();
    float d = acc - mu;
    red[t] = d * d;
    __syncthreads();
    for (int off = 128; off; off >>= 1) {
        if (t < off) red[t] += red[t + off];
        __syncthreads();
    }
    float var = red[0] / 256.f;
    float hn = d * rsqrtf(var + 1e-5f) * ln_g[t] + ln_b[t];
    hn = hn > 0.f ? hn : 0.f;
    __syncthreads();
    hs[t] = hn;
    __syncthreads();

    float acc2 = bs2[t];
    for (int k = 0; k < 256; k++) acc2 += hs[k] * Ws2[k * 256 + t];
    acc2 = acc2 > 0.f ? acc2 : 0.f;
    __syncthreads();
    hs[t] = acc2;
    __syncthreads();

    if (t < 16) {
        float a = ba[t];
        for (int k = 0; k < 256; k++) a += hs[k] * Wa[k * 16 + t];
        out_logits[b * 16 + t] = a;
    } else if (t == 16) {
        float v = bc[0];
        for (int k = 0; k < 256; k++) v += hs[k] * Wc[k];
        out_value[b] = v;
    }
}

// ---------------------------------------------------------------------------

extern "C" void kernel_launch(void* const* d_in, const int* in_sizes, int n_in,
                              void* d_out, int out_size, void* d_ws, size_t ws_size,
                              hipStream_t stream) {
    const float* obs    = (const float*)d_in[0];
    const float* nf     = (const float*)d_in[1];
    const int*   ei     = (const int*)d_in[2];
    const int*   batch  = (const int*)d_in[3];
    const float* W0     = (const float*)d_in[4];
    const float* a_src0 = (const float*)d_in[5];
    const float* a_dst0 = (const float*)d_in[6];
    const float* b0     = (const float*)d_in[7];
    const float* W1     = (const float*)d_in[8];
    const float* a_src1 = (const float*)d_in[9];
    const float* a_dst1 = (const float*)d_in[10];
    const float* b1     = (const float*)d_in[11];
    const float* W2     = (const float*)d_in[12];
    const float* a_src2 = (const float*)d_in[13];
    const float* a_dst2 = (const float*)d_in[14];
    const float* b2     = (const float*)d_in[15];
    const float* Ws1    = (const float*)d_in[16];
    const float* bs1    = (const float*)d_in[17];
    const float* ln_g   = (const float*)d_in[18];
    const float* ln_b   = (const float*)d_in[19];
    const float* Ws2    = (const float*)d_in[20];
    const float* bs2    = (const float*)d_in[21];
    const float* Wa     = (const float*)d_in[22];
    const float* ba     = (const float*)d_in[23];
    const float* Wc     = (const float*)d_in[24];
    const float* bc     = (const float*)d_in[25];

    const int N = in_sizes[3];
    const int E = in_sizes[2] / 2;
    const int B = in_sizes[0] / 128;
    const int* src = ei;
    const int* dstp = ei + E;

    // workspace carve (256B aligned) — footprint matches the known-good r6 layout
    char* p = (char*)d_ws;
    auto alloc = [&](size_t bytes) -> void* {
        void* r = (void*)p;
        p += (bytes + 255) & ~(size_t)255;
        return r;
    };
    int nb = (N + 255) / 256;
    int*   row_ptr   = (int*)alloc((size_t)(N + 1) * 4);
    int*   blockSums = (int*)alloc((size_t)(nb + 1) * 4);
    int*   col       = (int*)alloc((size_t)E * 4);
    unsigned short* hbuf = (unsigned short*)alloc((size_t)N * 128 * 2);  // bf16
    unsigned int*   xb   = (unsigned int*)alloc((size_t)N * 64 * 4);    // bf16x2 features
    float* xbuf      = (float*)alloc((size_t)N * 64 * 4);               // final layer fp32
    float* as_       = (float*)alloc((size_t)N * 2 * 4);
    float* ad_       = (float*)alloc((size_t)N * 2 * 4);
    unsigned short* Wf1 = (unsigned short*)alloc((size_t)8 * 4 * 64 * 8 * 2);
    unsigned short* Wf2 = (unsigned short*)alloc((size_t)4 * 4 * 64 * 8 * 2);
    float* pooled    = (float*)alloc((size_t)(B * 64 + B) * 4);
    float* cnt       = pooled + (size_t)B * 64;

    // cursor8 (8*N) + total (N) alias the xbuf region: CSR build completes
    // (stream-ordered) before xbuf's first write (agg1, last layer).
    int* cursor8 = (int*)xbuf;
    int* total   = cursor8 + (size_t)8 * N;

    float* out_logits = (float*)d_out;
    float* out_value  = out_logits + (size_t)B * 16;

    // ---- CSR build (by dst, real edges only; self-loops implicit in agg) ----
    hipMemsetAsync(cursor8, 0, (size_t)8 * N * 4, stream);
    int csr_blocks = (E + 8 * 256 - 1) / (8 * 256);
    int csr_T = csr_blocks * 256;
    count_kernel<<<csr_blocks, 256, 0, stream>>>(dstp, cursor8, E, csr_T, N);
    sum8_kernel<<<nb, 256, 0, stream>>>(cursor8, total, N);
    scan_block_kernel<<<nb, 256, 0, stream>>>(total, row_ptr, blockSums, N);
    scan_sums_kernel<<<1, 256, 0, stream>>>(blockSums, nb);
    scan_finalize_kernel<<<(N + 1 + 255) / 256, 256, 0, stream>>>(row_ptr, cursor8, blockSums, N, nb);
    scatter_kernel<<<csr_blocks, 256, 0, stream>>>(src, dstp, cursor8, col, E, csr_T, N);

    // ---- pack W fragments + zero pooled/cnt ----
    pack_w_kernel<128><<<8, 256, 0, stream>>>(W1, Wf1);
    pack_w_kernel<64><<<4, 256, 0, stream>>>(W2, Wf2);
    hipMemsetAsync(pooled, 0, (size_t)(B * 64 + B) * 4, stream);

    // ---- GAT layer 0: in=8 -> h=[N,2,64] concat, elu ----
    transform_kernel<8, 128, 2><<<(N + 7) / 8, 128, 0, stream>>>(
        nf, W0, a_src0, a_dst0, hbuf, as_, ad_, N);
    agg2_kernel<1><<<(N + 3) / 4, 256, 0, stream>>>(
        row_ptr, col, (const unsigned int*)hbuf, (const float2*)as_,
        (const float2*)ad_, b0, xb, N);

    // ---- GAT layer 1: in=128 -> concat, elu (MFMA transform) ----
    transform_mfma_kernel<128, 2><<<(N + 63) / 64, 256, 0, stream>>>(
        (const unsigned short*)xb, Wf1, a_src1, a_dst1, hbuf, as_, ad_, N);
    agg2_kernel<1><<<(N + 3) / 4, 256, 0, stream>>>(
        row_ptr, col, (const unsigned int*)hbuf, (const float2*)as_,
        (const float2*)ad_, b1, xb, N);

    // ---- GAT layer 2: in=128 -> heads=1, out=64 (MFMA transform) ----
    transform_mfma_kernel<64, 1><<<(N + 63) / 64, 256, 0, stream>>>(
        (const unsigned short*)xb, Wf2, a_src2, a_dst2, hbuf, as_, ad_, N);
    agg1_kernel<<<(N + 3) / 4, 256, 0, stream>>>(
        row_ptr, col, (const unsigned int*)hbuf, as_, ad_, b2, xbuf, N);

    // ---- mean pool + MLP head ----
    {
        int waves = (N + 15) / 16;
        int blocks = (waves + 3) / 4;
        pool_kernel<<<blocks, 256, 0, stream>>>(xbuf, batch, pooled, cnt, N);
    }
    mlp_kernel<<<B, 256, 0, stream>>>(pooled, cnt, obs, Ws1, bs1, ln_g, ln_b,
                                      Ws2, bs2, Wa, ba, Wc, bc,
                                      out_logits, out_value);
}